// Round 1
// baseline (271.231 us; speedup 1.0000x reference)
//
#include <hip/hip_runtime.h>
#include <stdint.h>

#define HW      16384   // 128*128
#define WIDTH   128
#define NTOPK   300
#define NLINES  10000
#define MPAD    10112   // 79*128

typedef unsigned short u16;
typedef unsigned int   u32;
typedef unsigned long long u64;
typedef __bf16 bf16x8 __attribute__((ext_vector_type(8)));
typedef float  f32x4  __attribute__((ext_vector_type(4)));

__device__ __forceinline__ u16 f2bf(float f) {
  u32 x = __builtin_bit_cast(u32, f);
  x += 0x7FFFu + ((x >> 16) & 1u);
  return (u16)(x >> 16);
}
__device__ __forceinline__ float bf2f(u32 u) {
  return __builtin_bit_cast(float, u << 16);
}
__device__ __forceinline__ void gload_lds16(void* lds, const void* g) {
  __builtin_amdgcn_global_load_lds(
      (const __attribute__((address_space(1))) void*)g,
      (__attribute__((address_space(3))) void*)lds, 16, 0, 0);
}

// ---------------- stage 1: jloc / joff ----------------
__global__ __launch_bounds__(256) void k_prep(const float* __restrict__ out9,
                                              float* __restrict__ jloc,
                                              float* __restrict__ joffx,
                                              float* __restrict__ joffy) {
  int i = blockIdx.x * 256 + threadIdx.x;
  if (i >= HW) return;
  float o5 = out9[5 * HW + i], o6 = out9[6 * HW + i];
  float o7 = out9[7 * HW + i], o8 = out9[8 * HW + i];
  jloc[i]  = 1.f / (1.f + expf(o5 - o6));        // softmax[1] == sigmoid(o6-o5)
  joffx[i] = 1.f / (1.f + expf(-o7)) - 0.5f;
  joffy[i] = 1.f / (1.f + expf(-o8)) - 0.5f;
}

// ---------------- stage 2: 3x3 NMS ----------------
__global__ __launch_bounds__(256) void k_nms(const float* __restrict__ jloc,
                                             float* __restrict__ jnms) {
  int i = blockIdx.x * 256 + threadIdx.x;
  if (i >= HW) return;
  int x = i & (WIDTH - 1), y = i >> 7;
  float a = jloc[i], m = a;
  for (int dy = -1; dy <= 1; ++dy) {
    int yy = y + dy;
    if (yy < 0 || yy >= WIDTH) continue;
    for (int dx = -1; dx <= 1; ++dx) {
      int xx = x + dx;
      if (xx < 0 || xx >= WIDTH) continue;
      m = fmaxf(m, jloc[yy * WIDTH + xx]);
    }
  }
  jnms[i] = (a == m) ? a : 0.f;
}

// ---------------- stage 3: top-300 via compact + bitonic sort ----------------
__global__ __launch_bounds__(1024) void k_topk(const float* __restrict__ jnms,
                                               const float* __restrict__ joffx,
                                               const float* __restrict__ joffy,
                                               float* __restrict__ juncs_ws,
                                               float* __restrict__ out_juncs,
                                               float* __restrict__ out_jsc) {
  __shared__ u64 keys[4096];
  __shared__ int cnt;
  int t = threadIdx.x;
  if (t == 0) cnt = 0;
  __syncthreads();
  for (int i = t; i < HW; i += 1024) {
    float v = jnms[i];
    if (v > 0.f) {
      int pos = atomicAdd(&cnt, 1);
      if (pos < 4096)
        keys[pos] = ((u64)__builtin_bit_cast(u32, v) << 32) | (u32)(0xFFFFFFFFu - (u32)i);
    }
  }
  __syncthreads();
  int c = cnt < 4096 ? cnt : 4096;
  for (int i = t; i < 4096; i += 1024)
    if (i >= c) keys[i] = 0ull;
  __syncthreads();
  // bitonic sort, descending
  for (int k = 2; k <= 4096; k <<= 1) {
    for (int j = k >> 1; j > 0; j >>= 1) {
      for (int u = t; u < 2048; u += 1024) {
        int i  = ((u & ~(j - 1)) << 1) | (u & (j - 1));
        int p  = i | j;
        u64 a = keys[i], b = keys[p];
        bool dir = (i & k) == 0;           // descending blocks
        if ((a < b) == dir) { keys[i] = b; keys[p] = a; }
      }
      __syncthreads();
    }
  }
  if (t < NTOPK) {
    u64 key = keys[t];
    u32 vb  = (u32)(key >> 32);
    int idx = (int)(0xFFFFFFFFu - (u32)(key & 0xFFFFFFFFu));
    float x = (float)(idx & (WIDTH - 1)) + joffx[idx] + 0.5f;
    float y = (float)(idx >> 7)          + joffy[idx] + 0.5f;
    juncs_ws[2 * t] = x; juncs_ws[2 * t + 1] = y;
    out_juncs[2 * t] = x; out_juncs[2 * t + 1] = y;
    out_jsc[t] = __builtin_bit_cast(float, vb);
  }
}

// ---------------- stage 4: endpoint matching ----------------
__global__ __launch_bounds__(256) void k_match(const float* __restrict__ juncs,
                                               const float* __restrict__ lines_pred,
                                               float* __restrict__ lines_adj,
                                               float* __restrict__ keepf) {
  __shared__ float jl[2 * NTOPK];
  for (int i = threadIdx.x; i < 2 * NTOPK; i += 256) jl[i] = juncs[i];
  __syncthreads();
  int l = blockIdx.x * 256 + threadIdx.x;
  if (l >= NLINES) return;
  float lx1 = lines_pred[l * 4 + 0], ly1 = lines_pred[l * 4 + 1];
  float lx2 = lines_pred[l * 4 + 2], ly2 = lines_pred[l * 4 + 3];
  float b1 = __builtin_inff(), b2 = __builtin_inff();
  int i1 = 0, i2 = 0;
  for (int j = 0; j < NTOPK; ++j) {
    float jx = jl[2 * j], jy = jl[2 * j + 1];
    // no-FMA: match numpy (a-b)^2 sum bitwise
    float dx = __fsub_rn(lx1, jx), dy = __fsub_rn(ly1, jy);
    float d  = __fadd_rn(__fmul_rn(dx, dx), __fmul_rn(dy, dy));
    if (d < b1) { b1 = d; i1 = j; }
    dx = __fsub_rn(lx2, jx); dy = __fsub_rn(ly2, jy);
    d  = __fadd_rn(__fmul_rn(dx, dx), __fmul_rn(dy, dy));
    if (d < b2) { b2 = d; i2 = j; }
  }
  int imin = i1 < i2 ? i1 : i2;
  int imax = i1 < i2 ? i2 : i1;
  lines_adj[l * 4 + 0] = jl[2 * imin];
  lines_adj[l * 4 + 1] = jl[2 * imin + 1];
  lines_adj[l * 4 + 2] = jl[2 * imax];
  lines_adj[l * 4 + 3] = jl[2 * imax + 1];
  keepf[l] = (imin < imax) ? 1.f : 0.f;
}

// ---------------- stage 5: loi = fc1_w @ features + fc1_b, stored pixel-major ----------------
__global__ __launch_bounds__(256) void k_loi(const float* __restrict__ features,
                                             const float* __restrict__ fc1w,
                                             const float* __restrict__ fc1b,
                                             float* __restrict__ loi) {
  __shared__ float ft[64][64];   // [c][p]
  __shared__ float wt[128][64];  // [d][c]
  int t = threadIdx.x;
  int p0 = blockIdx.x * 64;
  int lane = t & 63, g = t >> 6;     // g in 0..3 -> d block of 32
  float acc[32];
#pragma unroll
  for (int i = 0; i < 32; ++i) acc[i] = 0.f;
  for (int c0 = 0; c0 < 256; c0 += 64) {
    __syncthreads();
#pragma unroll
    for (int i = 0; i < 4; ++i) {           // features tile 64c x 64p
      int lin = i * 256 + t;
      int c = lin >> 4, p4 = (lin & 15) << 2;
      *(float4*)&ft[c][p4] = *(const float4*)&features[(size_t)(c0 + c) * HW + p0 + p4];
    }
#pragma unroll
    for (int i = 0; i < 8; ++i) {           // weight tile 128d x 64c
      int lin = i * 256 + t;
      int d = lin >> 4, c4 = (lin & 15) << 2;
      *(float4*)&wt[d][c4] = *(const float4*)&fc1w[(size_t)d * 256 + c0 + c4];
    }
    __syncthreads();
    for (int c = 0; c < 64; ++c) {
      float f = ft[c][lane];
#pragma unroll
      for (int dd = 0; dd < 32; ++dd) acc[dd] += wt[g * 32 + dd][c] * f;
    }
  }
  int p = p0 + lane;
#pragma unroll
  for (int dd = 0; dd < 32; ++dd) acc[dd] += fc1b[g * 32 + dd];
#pragma unroll
  for (int i = 0; i < 8; ++i) {
    float4 v = make_float4(acc[i * 4], acc[i * 4 + 1], acc[i * 4 + 2], acc[i * 4 + 3]);
    *(float4*)&loi[(size_t)p * 128 + g * 32 + i * 4] = v;
  }
}

// ---------------- stage 6: line pooling -> feat bf16 (NLINES x 1024) ----------------
__global__ __launch_bounds__(256) void k_interp(const float* __restrict__ loi,
                                                const float* __restrict__ lines_adj,
                                                u16* __restrict__ feat) {
  __shared__ int   tap[32][4];
  __shared__ float wgt[32][4];
  int l = blockIdx.x;
  int t = threadIdx.x;
  if (t < 32) {
    float ux = lines_adj[l * 4 + 0], uy = lines_adj[l * 4 + 1];
    float vx = lines_adj[l * 4 + 2], vy = lines_adj[l * 4 + 3];
    float tt = (float)t / 31.f;
    float px = ux * tt + vx * (1.f - tt) - 0.5f;
    float py = uy * tt + vy * (1.f - tt) - 0.5f;
    float px0 = fminf(fmaxf(floorf(px), 0.f), 127.f);
    float py0 = fminf(fmaxf(floorf(py), 0.f), 127.f);
    float px1 = fminf(px0 + 1.f, 127.f);
    float py1 = fminf(py0 + 1.f, 127.f);
    int ix0 = (int)px0, iy0 = (int)py0, ix1 = (int)px1, iy1 = (int)py1;
    tap[t][0] = (iy0 * WIDTH + ix0) * 128;
    tap[t][1] = (iy1 * WIDTH + ix0) * 128;
    tap[t][2] = (iy0 * WIDTH + ix1) * 128;
    tap[t][3] = (iy1 * WIDTH + ix1) * 128;
    float wy1 = py1 - py, wy0 = py - py0, wx1 = px1 - px, wx0 = px - px0;
    wgt[t][0] = wy1 * wx1; wgt[t][1] = wy0 * wx1;
    wgt[t][2] = wy1 * wx0; wgt[t][3] = wy0 * wx0;
  }
  __syncthreads();
  int d = t >> 1, sg = (t & 1) * 4;
  u16 o[4];
#pragma unroll
  for (int si = 0; si < 4; ++si) {
    int s = sg + si;
    float mx = -__builtin_inff();
#pragma unroll
    for (int k = 0; k < 4; ++k) {
      int j = s * 4 + k;
      float v = loi[tap[j][0] + d] * wgt[j][0] + loi[tap[j][1] + d] * wgt[j][1]
              + loi[tap[j][2] + d] * wgt[j][2] + loi[tap[j][3] + d] * wgt[j][3];
      mx = fmaxf(mx, v);
    }
    o[si] = f2bf(mx);
  }
  uint2 pk;
  pk.x = (u32)o[0] | ((u32)o[1] << 16);
  pk.y = (u32)o[2] | ((u32)o[3] << 16);
  *(uint2*)&feat[(size_t)l * 1024 + d * 8 + sg] = pk;
}

// ---------------- f32 -> bf16 weight convert ----------------
__global__ __launch_bounds__(256) void k_cvt(const float* __restrict__ src,
                                             u16* __restrict__ dst, int n) {
  int i = (blockIdx.x * 256 + threadIdx.x) * 4;
  if (i >= n) return;
  float4 v = *(const float4*)&src[i];
  uint2 pk;
  pk.x = (u32)f2bf(v.x) | ((u32)f2bf(v.y) << 16);
  pk.y = (u32)f2bf(v.z) | ((u32)f2bf(v.w) << 16);
  *(uint2*)&dst[i] = pk;
}

// ---------------- m97-style bf16 GEMM:  C = act(A @ B^T + bias) ----------------
// A: M x K row-major bf16, B: N x K row-major bf16, C: M x N bf16.  M%128==0, N%128==0, K%32==0
template <int RELU>
__global__ __launch_bounds__(256) void k_gemm(const u16* __restrict__ A,
                                              const u16* __restrict__ B,
                                              const float* __restrict__ bias,
                                              u16* __restrict__ C,
                                              int M, int N, int K) {
  __shared__ u16 Alds[128 * 32];
  __shared__ u16 Blds[128 * 32];
  int t = threadIdx.x;
  int tm0 = blockIdx.x * 128;
  int tn0 = blockIdx.y * 128;
  int lane = t & 63, wid = t >> 6;
  int wr = wid >> 1, wc = wid & 1;
  f32x4 acc[4][4] = {};
  int arow = t >> 2, apos = (t & 3) * 8;   // staging: 4 threads/row, 8 bf16 each
  const u16* Abase = A + (size_t)tm0 * K;
  const u16* Bbase = B + (size_t)tn0 * K;
  int r = lane & 15, ks = (lane >> 4) * 8;
  for (int k0 = 0; k0 < K; k0 += 32) {
    gload_lds16(&Alds[(size_t)t * 8],         Abase + (size_t)arow * K + k0 + apos);
    gload_lds16(&Alds[(size_t)(t + 256) * 8], Abase + (size_t)(arow + 64) * K + k0 + apos);
    gload_lds16(&Blds[(size_t)t * 8],         Bbase + (size_t)arow * K + k0 + apos);
    gload_lds16(&Blds[(size_t)(t + 256) * 8], Bbase + (size_t)(arow + 64) * K + k0 + apos);
    __syncthreads();
    bf16x8 af[4], bfr[4];
#pragma unroll
    for (int i = 0; i < 4; ++i) {
      af[i]  = *(const bf16x8*)&Alds[(wr * 64 + i * 16 + r) * 32 + ks];
      bfr[i] = *(const bf16x8*)&Blds[(wc * 64 + i * 16 + r) * 32 + ks];
    }
#pragma unroll
    for (int mi = 0; mi < 4; ++mi)
#pragma unroll
      for (int ni = 0; ni < 4; ++ni)
        acc[mi][ni] = __builtin_amdgcn_mfma_f32_16x16x32_bf16(af[mi], bfr[ni], acc[mi][ni], 0, 0, 0);
    __syncthreads();
  }
  int rsub = (lane >> 4) * 4, csub = lane & 15;
#pragma unroll
  for (int mi = 0; mi < 4; ++mi) {
#pragma unroll
    for (int ni = 0; ni < 4; ++ni) {
      int col = tn0 + wc * 64 + ni * 16 + csub;
      float bv = bias[col];
#pragma unroll
      for (int j = 0; j < 4; ++j) {
        int row = tm0 + wr * 64 + mi * 16 + rsub + j;
        float v = acc[mi][ni][j] + bv;
        if (RELU) v = fmaxf(v, 0.f);
        C[(size_t)row * N + col] = f2bf(v);
      }
    }
  }
}

// ---------------- stage 9: logits + sigmoid * keep ----------------
__global__ __launch_bounds__(256) void k_head(const u16* __restrict__ hid2,
                                              const float* __restrict__ w3,
                                              const float* __restrict__ b3,
                                              const float* __restrict__ keepf,
                                              float* __restrict__ scores) {
  int wid = threadIdx.x >> 6, lane = threadIdx.x & 63;
  int l = blockIdx.x * 4 + wid;
  if (l >= NLINES) return;
  const u16* row = hid2 + (size_t)l * 1024;
  float acc = 0.f;
#pragma unroll
  for (int i = 0; i < 4; ++i) {
    int base = i * 256 + lane * 4;
    uint2 hv = *(const uint2*)&row[base];
    float4 wv = *(const float4*)&w3[base];
    acc += bf2f(hv.x & 0xffffu) * wv.x + bf2f(hv.x >> 16) * wv.y
         + bf2f(hv.y & 0xffffu) * wv.z + bf2f(hv.y >> 16) * wv.w;
  }
#pragma unroll
  for (int off = 32; off; off >>= 1) acc += __shfl_down(acc, off, 64);
  if (lane == 0) {
    float logit = acc + b3[0];
    float s = 1.f / (1.f + expf(-logit));
    scores[l] = s * keepf[l];
  }
}

extern "C" void kernel_launch(void* const* d_in, const int* in_sizes, int n_in,
                              void* d_out, int out_size, void* d_ws, size_t ws_size,
                              hipStream_t stream) {
  const float* t_output   = (const float*)d_in[0];
  const float* t_features = (const float*)d_in[1];
  const float* t_lines    = (const float*)d_in[2];
  const float* t_fc1w     = (const float*)d_in[3];
  const float* t_fc1b     = (const float*)d_in[4];
  const float* t_w1       = (const float*)d_in[5];
  const float* t_b1       = (const float*)d_in[6];
  const float* t_w2       = (const float*)d_in[7];
  const float* t_b2       = (const float*)d_in[8];
  const float* t_w3       = (const float*)d_in[9];
  const float* t_b3       = (const float*)d_in[10];

  // workspace layout (~54.3 MB)
  char* w = (char*)d_ws;
  float* loi   = (float*)w;                       // 16384*128 f32 = 8 MB
  float* jloc  = (float*)(w + 8388608);
  float* jnms  = jloc + HW;
  float* joffx = jnms + HW;
  float* joffy = joffx + HW;
  float* juncs = joffy + HW;                      // 600 f32 (pad 1024)
  float* keepf = juncs + 1024;                    // 10000 f32 (pad 10240)
  u16* w1b  = (u16*)(keepf + 10240);              // 1M bf16
  u16* w2b  = w1b + 1048576;
  u16* feat = w2b + 1048576;                      // MPAD*1024 bf16
  u16* hid1 = feat + (size_t)MPAD * 1024;
  u16* hid2 = feat;                               // reuse feat buffer

  float* out_scores = (float*)d_out;              // 10000
  float* out_ladj   = out_scores + NLINES;        // 40000
  float* out_juncs  = out_scores + 50000;         // 600
  float* out_jsc    = out_scores + 50600;         // 300

  k_prep<<<64, 256, 0, stream>>>(t_output, jloc, joffx, joffy);
  k_nms<<<64, 256, 0, stream>>>(jloc, jnms);
  k_topk<<<1, 1024, 0, stream>>>(jnms, joffx, joffy, juncs, out_juncs, out_jsc);
  k_match<<<40, 256, 0, stream>>>(juncs, t_lines, out_ladj, keepf);
  k_loi<<<256, 256, 0, stream>>>(t_features, t_fc1w, t_fc1b, loi);
  k_interp<<<NLINES, 256, 0, stream>>>(loi, out_ladj, feat);
  k_cvt<<<1024, 256, 0, stream>>>(t_w1, w1b, 1048576);
  k_cvt<<<1024, 256, 0, stream>>>(t_w2, w2b, 1048576);
  k_gemm<1><<<dim3(MPAD / 128, 8), 256, 0, stream>>>(feat, w1b, t_b1, hid1, MPAD, 1024, 1024);
  k_gemm<1><<<dim3(MPAD / 128, 8), 256, 0, stream>>>(hid1, w2b, t_b2, hid2, MPAD, 1024, 1024);
  k_head<<<2500, 256, 0, stream>>>(hid2, t_w3, t_b3, keepf, out_scores);
}

// Round 2
// 220.991 us; speedup vs baseline: 1.2273x; 1.2273x over previous
//
#include <hip/hip_runtime.h>
#include <stdint.h>

#define HW      16384   // 128*128
#define WIDTH   128
#define NTOPK   300
#define NLINES  10000
#define MPAD    10112   // 79*128

typedef unsigned short u16;
typedef unsigned int   u32;
typedef unsigned long long u64;
typedef __bf16 bf16x8 __attribute__((ext_vector_type(8)));
typedef float  f32x4  __attribute__((ext_vector_type(4)));

__device__ __forceinline__ u16 f2bf(float f) {
  u32 x = __builtin_bit_cast(u32, f);
  x += 0x7FFFu + ((x >> 16) & 1u);
  return (u16)(x >> 16);
}
__device__ __forceinline__ float bf2f(u32 u) {
  return __builtin_bit_cast(float, u << 16);
}
__device__ __forceinline__ void gload_lds16(void* lds, const void* g) {
  __builtin_amdgcn_global_load_lds(
      (const __attribute__((address_space(1))) void*)g,
      (__attribute__((address_space(3))) void*)lds, 16, 0, 0);
}

// ---------------- stage 1: jloc / joff ----------------
__global__ __launch_bounds__(256) void k_prep(const float* __restrict__ out9,
                                              float* __restrict__ jloc,
                                              float* __restrict__ joffx,
                                              float* __restrict__ joffy) {
  int i = blockIdx.x * 256 + threadIdx.x;
  if (i >= HW) return;
  float o5 = out9[5 * HW + i], o6 = out9[6 * HW + i];
  float o7 = out9[7 * HW + i], o8 = out9[8 * HW + i];
  jloc[i]  = 1.f / (1.f + expf(o5 - o6));        // softmax[1] == sigmoid(o6-o5)
  joffx[i] = 1.f / (1.f + expf(-o7)) - 0.5f;
  joffy[i] = 1.f / (1.f + expf(-o8)) - 0.5f;
}

// ---------------- stage 2: 3x3 NMS ----------------
__global__ __launch_bounds__(256) void k_nms(const float* __restrict__ jloc,
                                             float* __restrict__ jnms) {
  int i = blockIdx.x * 256 + threadIdx.x;
  if (i >= HW) return;
  int x = i & (WIDTH - 1), y = i >> 7;
  float a = jloc[i], m = a;
  for (int dy = -1; dy <= 1; ++dy) {
    int yy = y + dy;
    if (yy < 0 || yy >= WIDTH) continue;
    for (int dx = -1; dx <= 1; ++dx) {
      int xx = x + dx;
      if (xx < 0 || xx >= WIDTH) continue;
      m = fmaxf(m, jloc[yy * WIDTH + xx]);
    }
  }
  jnms[i] = (a == m) ? a : 0.f;
}

// ---------------- stage 3: top-300 via compact + bitonic sort ----------------
__global__ __launch_bounds__(1024) void k_topk(const float* __restrict__ jnms,
                                               const float* __restrict__ joffx,
                                               const float* __restrict__ joffy,
                                               float* __restrict__ juncs_ws,
                                               float* __restrict__ out_juncs,
                                               float* __restrict__ out_jsc) {
  __shared__ u64 keys[4096];
  __shared__ int cnt;
  int t = threadIdx.x;
  if (t == 0) cnt = 0;
  __syncthreads();
  for (int i = t; i < HW; i += 1024) {
    float v = jnms[i];
    if (v > 0.f) {
      int pos = atomicAdd(&cnt, 1);
      if (pos < 4096)
        keys[pos] = ((u64)__builtin_bit_cast(u32, v) << 32) | (u32)(0xFFFFFFFFu - (u32)i);
    }
  }
  __syncthreads();
  int c = cnt < 4096 ? cnt : 4096;
  for (int i = t; i < 4096; i += 1024)
    if (i >= c) keys[i] = 0ull;
  __syncthreads();
  // bitonic sort, descending
  for (int k = 2; k <= 4096; k <<= 1) {
    for (int j = k >> 1; j > 0; j >>= 1) {
      for (int u = t; u < 2048; u += 1024) {
        int i  = ((u & ~(j - 1)) << 1) | (u & (j - 1));
        int p  = i | j;
        u64 a = keys[i], b = keys[p];
        bool dir = (i & k) == 0;           // descending blocks
        if ((a < b) == dir) { keys[i] = b; keys[p] = a; }
      }
      __syncthreads();
    }
  }
  if (t < NTOPK) {
    u64 key = keys[t];
    u32 vb  = (u32)(key >> 32);
    int idx = (int)(0xFFFFFFFFu - (u32)(key & 0xFFFFFFFFu));
    float x = (float)(idx & (WIDTH - 1)) + joffx[idx] + 0.5f;
    float y = (float)(idx >> 7)          + joffy[idx] + 0.5f;
    juncs_ws[2 * t] = x; juncs_ws[2 * t + 1] = y;
    out_juncs[2 * t] = x; out_juncs[2 * t + 1] = y;
    out_jsc[t] = __builtin_bit_cast(float, vb);
  }
}

// ---------------- stage 4: endpoint matching ----------------
__global__ __launch_bounds__(256) void k_match(const float* __restrict__ juncs,
                                               const float* __restrict__ lines_pred,
                                               float* __restrict__ lines_adj,
                                               float* __restrict__ keepf) {
  __shared__ float jl[2 * NTOPK];
  for (int i = threadIdx.x; i < 2 * NTOPK; i += 256) jl[i] = juncs[i];
  __syncthreads();
  int l = blockIdx.x * 256 + threadIdx.x;
  if (l >= NLINES) return;
  float lx1 = lines_pred[l * 4 + 0], ly1 = lines_pred[l * 4 + 1];
  float lx2 = lines_pred[l * 4 + 2], ly2 = lines_pred[l * 4 + 3];
  float b1 = __builtin_inff(), b2 = __builtin_inff();
  int i1 = 0, i2 = 0;
  for (int j = 0; j < NTOPK; ++j) {
    float jx = jl[2 * j], jy = jl[2 * j + 1];
    // no-FMA: match numpy (a-b)^2 sum bitwise
    float dx = __fsub_rn(lx1, jx), dy = __fsub_rn(ly1, jy);
    float d  = __fadd_rn(__fmul_rn(dx, dx), __fmul_rn(dy, dy));
    if (d < b1) { b1 = d; i1 = j; }
    dx = __fsub_rn(lx2, jx); dy = __fsub_rn(ly2, jy);
    d  = __fadd_rn(__fmul_rn(dx, dx), __fmul_rn(dy, dy));
    if (d < b2) { b2 = d; i2 = j; }
  }
  int imin = i1 < i2 ? i1 : i2;
  int imax = i1 < i2 ? i2 : i1;
  lines_adj[l * 4 + 0] = jl[2 * imin];
  lines_adj[l * 4 + 1] = jl[2 * imin + 1];
  lines_adj[l * 4 + 2] = jl[2 * imax];
  lines_adj[l * 4 + 3] = jl[2 * imax + 1];
  keepf[l] = (imin < imax) ? 1.f : 0.f;
}

// ---------------- stage 5: loi = fc1_w @ features + fc1_b -> bf16, pixel-major ----------------
__global__ __launch_bounds__(256) void k_loi(const float* __restrict__ features,
                                             const float* __restrict__ fc1w,
                                             const float* __restrict__ fc1b,
                                             u16* __restrict__ loib) {
  __shared__ float ft[64][64];   // [c][p]
  __shared__ float wt[128][64];  // [d][c]
  int t = threadIdx.x;
  int p0 = blockIdx.x * 64;
  int lane = t & 63, g = t >> 6;     // g in 0..3 -> d block of 32
  float acc[32];
#pragma unroll
  for (int i = 0; i < 32; ++i) acc[i] = 0.f;
  for (int c0 = 0; c0 < 256; c0 += 64) {
    __syncthreads();
#pragma unroll
    for (int i = 0; i < 4; ++i) {           // features tile 64c x 64p
      int lin = i * 256 + t;
      int c = lin >> 4, p4 = (lin & 15) << 2;
      *(float4*)&ft[c][p4] = *(const float4*)&features[(size_t)(c0 + c) * HW + p0 + p4];
    }
#pragma unroll
    for (int i = 0; i < 8; ++i) {           // weight tile 128d x 64c
      int lin = i * 256 + t;
      int d = lin >> 4, c4 = (lin & 15) << 2;
      *(float4*)&wt[d][c4] = *(const float4*)&fc1w[(size_t)d * 256 + c0 + c4];
    }
    __syncthreads();
    for (int c = 0; c < 64; ++c) {
      float f = ft[c][lane];
#pragma unroll
      for (int dd = 0; dd < 32; ++dd) acc[dd] += wt[g * 32 + dd][c] * f;
    }
  }
  int p = p0 + lane;
#pragma unroll
  for (int dd = 0; dd < 32; ++dd) acc[dd] += fc1b[g * 32 + dd];
#pragma unroll
  for (int i = 0; i < 4; ++i) {   // pack 8 bf16 per 16B store
    uint4 pk;
    pk.x = (u32)f2bf(acc[i * 8 + 0]) | ((u32)f2bf(acc[i * 8 + 1]) << 16);
    pk.y = (u32)f2bf(acc[i * 8 + 2]) | ((u32)f2bf(acc[i * 8 + 3]) << 16);
    pk.z = (u32)f2bf(acc[i * 8 + 4]) | ((u32)f2bf(acc[i * 8 + 5]) << 16);
    pk.w = (u32)f2bf(acc[i * 8 + 6]) | ((u32)f2bf(acc[i * 8 + 7]) << 16);
    *(uint4*)&loib[(size_t)p * 128 + g * 32 + i * 8] = pk;
  }
}

// ---------------- stage 6: line pooling -> feat bf16 (NLINES x 1024) ----------------
// loib: bf16 pixel-major [16384][128]. One block per line.
// Wave w handles maxpool groups s = w (iter0) and s = w+4 (iter1).
// lane = q*16 + chgrp: q = point-within-group, chgrp = 8-channel group.
__device__ __forceinline__ void acc8(uint4 r, float wg, float* a) {
  a[0] += bf2f(r.x & 0xffffu) * wg; a[1] += bf2f(r.x >> 16) * wg;
  a[2] += bf2f(r.y & 0xffffu) * wg; a[3] += bf2f(r.y >> 16) * wg;
  a[4] += bf2f(r.z & 0xffffu) * wg; a[5] += bf2f(r.z >> 16) * wg;
  a[6] += bf2f(r.w & 0xffffu) * wg; a[7] += bf2f(r.w >> 16) * wg;
}
__global__ __launch_bounds__(256) void k_interp(const u16* __restrict__ loib,
                                                const float* __restrict__ lines_adj,
                                                u16* __restrict__ feat) {
  __shared__ u16 outb[8][128];   // [group s][channel]
  int l = blockIdx.x;
  int t = threadIdx.x;
  int w = t >> 6, lane = t & 63;
  int q = lane >> 4, chgrp = lane & 15;
  float ux = lines_adj[l * 4 + 0], uy = lines_adj[l * 4 + 1];
  float vx = lines_adj[l * 4 + 2], vy = lines_adj[l * 4 + 3];
#pragma unroll
  for (int it = 0; it < 2; ++it) {
    int s = it * 4 + w;
    int p = s * 4 + q;
    float tt = (float)p / 31.f;
    float px = ux * tt + vx * (1.f - tt) - 0.5f;
    float py = uy * tt + vy * (1.f - tt) - 0.5f;
    float px0 = fminf(fmaxf(floorf(px), 0.f), 127.f);
    float py0 = fminf(fmaxf(floorf(py), 0.f), 127.f);
    float px1 = fminf(px0 + 1.f, 127.f);
    float py1 = fminf(py0 + 1.f, 127.f);
    int ix0 = (int)px0, iy0 = (int)py0, ix1 = (int)px1, iy1 = (int)py1;
    float wy1 = py1 - py, wy0 = py - py0, wx1 = px1 - px, wx0 = px - px0;
    int co = chgrp * 8;
    const u16* r00 = &loib[(iy0 * WIDTH + ix0) * 128 + co];
    const u16* r10 = &loib[(iy1 * WIDTH + ix0) * 128 + co];
    const u16* r01 = &loib[(iy0 * WIDTH + ix1) * 128 + co];
    const u16* r11 = &loib[(iy1 * WIDTH + ix1) * 128 + co];
    uint4 v00 = *(const uint4*)r00;
    uint4 v10 = *(const uint4*)r10;
    uint4 v01 = *(const uint4*)r01;
    uint4 v11 = *(const uint4*)r11;
    float a[8];
#pragma unroll
    for (int c = 0; c < 8; ++c) a[c] = 0.f;
    acc8(v00, wy1 * wx1, a);
    acc8(v10, wy0 * wx1, a);
    acc8(v01, wy1 * wx0, a);
    acc8(v11, wy0 * wx0, a);
    // maxpool over q (4 points) via shuffles
#pragma unroll
    for (int c = 0; c < 8; ++c) {
      float v = fmaxf(a[c], __shfl_xor(a[c], 16, 64));
      v = fmaxf(v, __shfl_xor(v, 32, 64));
      a[c] = v;
    }
    if (q == 0) {
      uint4 pk;
      pk.x = (u32)f2bf(a[0]) | ((u32)f2bf(a[1]) << 16);
      pk.y = (u32)f2bf(a[2]) | ((u32)f2bf(a[3]) << 16);
      pk.z = (u32)f2bf(a[4]) | ((u32)f2bf(a[5]) << 16);
      pk.w = (u32)f2bf(a[6]) | ((u32)f2bf(a[7]) << 16);
      *(uint4*)&outb[s][co] = pk;
    }
  }
  __syncthreads();
  // transpose [s][ch] -> feat[l][ch*8+s], coalesced uint2 stores
  int ch = t >> 1, s0 = (t & 1) * 4;
  u16 e0 = outb[s0 + 0][ch], e1 = outb[s0 + 1][ch];
  u16 e2 = outb[s0 + 2][ch], e3 = outb[s0 + 3][ch];
  uint2 pk;
  pk.x = (u32)e0 | ((u32)e1 << 16);
  pk.y = (u32)e2 | ((u32)e3 << 16);
  *(uint2*)&feat[(size_t)l * 1024 + ch * 8 + s0] = pk;
}

// ---------------- f32 -> bf16 weight convert ----------------
__global__ __launch_bounds__(256) void k_cvt(const float* __restrict__ src,
                                             u16* __restrict__ dst, int n) {
  int i = (blockIdx.x * 256 + threadIdx.x) * 4;
  if (i >= n) return;
  float4 v = *(const float4*)&src[i];
  uint2 pk;
  pk.x = (u32)f2bf(v.x) | ((u32)f2bf(v.y) << 16);
  pk.y = (u32)f2bf(v.z) | ((u32)f2bf(v.w) << 16);
  *(uint2*)&dst[i] = pk;
}

// ---------------- m97-style bf16 GEMM:  C = act(A @ B^T + bias) ----------------
// A: M x K row-major bf16, B: N x K row-major bf16, C: M x N bf16.  M%128==0, N%128==0, K%32==0
template <int RELU>
__global__ __launch_bounds__(256) void k_gemm(const u16* __restrict__ A,
                                              const u16* __restrict__ B,
                                              const float* __restrict__ bias,
                                              u16* __restrict__ C,
                                              int M, int N, int K) {
  __shared__ u16 Alds[128 * 32];
  __shared__ u16 Blds[128 * 32];
  int t = threadIdx.x;
  int tm0 = blockIdx.x * 128;
  int tn0 = blockIdx.y * 128;
  int lane = t & 63, wid = t >> 6;
  int wr = wid >> 1, wc = wid & 1;
  f32x4 acc[4][4] = {};
  int arow = t >> 2, apos = (t & 3) * 8;   // staging: 4 threads/row, 8 bf16 each
  const u16* Abase = A + (size_t)tm0 * K;
  const u16* Bbase = B + (size_t)tn0 * K;
  int r = lane & 15, ks = (lane >> 4) * 8;
  for (int k0 = 0; k0 < K; k0 += 32) {
    gload_lds16(&Alds[(size_t)t * 8],         Abase + (size_t)arow * K + k0 + apos);
    gload_lds16(&Alds[(size_t)(t + 256) * 8], Abase + (size_t)(arow + 64) * K + k0 + apos);
    gload_lds16(&Blds[(size_t)t * 8],         Bbase + (size_t)arow * K + k0 + apos);
    gload_lds16(&Blds[(size_t)(t + 256) * 8], Bbase + (size_t)(arow + 64) * K + k0 + apos);
    __syncthreads();
    bf16x8 af[4], bfr[4];
#pragma unroll
    for (int i = 0; i < 4; ++i) {
      af[i]  = *(const bf16x8*)&Alds[(wr * 64 + i * 16 + r) * 32 + ks];
      bfr[i] = *(const bf16x8*)&Blds[(wc * 64 + i * 16 + r) * 32 + ks];
    }
#pragma unroll
    for (int mi = 0; mi < 4; ++mi)
#pragma unroll
      for (int ni = 0; ni < 4; ++ni)
        acc[mi][ni] = __builtin_amdgcn_mfma_f32_16x16x32_bf16(af[mi], bfr[ni], acc[mi][ni], 0, 0, 0);
    __syncthreads();
  }
  int rsub = (lane >> 4) * 4, csub = lane & 15;
#pragma unroll
  for (int mi = 0; mi < 4; ++mi) {
#pragma unroll
    for (int ni = 0; ni < 4; ++ni) {
      int col = tn0 + wc * 64 + ni * 16 + csub;
      float bv = bias[col];
#pragma unroll
      for (int j = 0; j < 4; ++j) {
        int row = tm0 + wr * 64 + mi * 16 + rsub + j;
        float v = acc[mi][ni][j] + bv;
        if (RELU) v = fmaxf(v, 0.f);
        C[(size_t)row * N + col] = f2bf(v);
      }
    }
  }
}

// ---------------- stage 9: logits + sigmoid * keep ----------------
__global__ __launch_bounds__(256) void k_head(const u16* __restrict__ hid2,
                                              const float* __restrict__ w3,
                                              const float* __restrict__ b3,
                                              const float* __restrict__ keepf,
                                              float* __restrict__ scores) {
  int wid = threadIdx.x >> 6, lane = threadIdx.x & 63;
  int l = blockIdx.x * 4 + wid;
  if (l >= NLINES) return;
  const u16* row = hid2 + (size_t)l * 1024;
  float acc = 0.f;
#pragma unroll
  for (int i = 0; i < 4; ++i) {
    int base = i * 256 + lane * 4;
    uint2 hv = *(const uint2*)&row[base];
    float4 wv = *(const float4*)&w3[base];
    acc += bf2f(hv.x & 0xffffu) * wv.x + bf2f(hv.x >> 16) * wv.y
         + bf2f(hv.y & 0xffffu) * wv.z + bf2f(hv.y >> 16) * wv.w;
  }
#pragma unroll
  for (int off = 32; off; off >>= 1) acc += __shfl_down(acc, off, 64);
  if (lane == 0) {
    float logit = acc + b3[0];
    float s = 1.f / (1.f + expf(-logit));
    scores[l] = s * keepf[l];
  }
}

extern "C" void kernel_launch(void* const* d_in, const int* in_sizes, int n_in,
                              void* d_out, int out_size, void* d_ws, size_t ws_size,
                              hipStream_t stream) {
  const float* t_output   = (const float*)d_in[0];
  const float* t_features = (const float*)d_in[1];
  const float* t_lines    = (const float*)d_in[2];
  const float* t_fc1w     = (const float*)d_in[3];
  const float* t_fc1b     = (const float*)d_in[4];
  const float* t_w1       = (const float*)d_in[5];
  const float* t_b1       = (const float*)d_in[6];
  const float* t_w2       = (const float*)d_in[7];
  const float* t_b2       = (const float*)d_in[8];
  const float* t_w3       = (const float*)d_in[9];
  const float* t_b3       = (const float*)d_in[10];

  // workspace layout (~50 MB)
  char* w = (char*)d_ws;
  u16*   loib  = (u16*)w;                         // 16384*128 bf16 = 4 MB
  float* jloc  = (float*)(w + 4194304);
  float* jnms  = jloc + HW;
  float* joffx = jnms + HW;
  float* joffy = joffx + HW;
  float* juncs = joffy + HW;                      // 600 f32 (pad 1024)
  float* keepf = juncs + 1024;                    // 10000 f32 (pad 10240)
  u16* w1b  = (u16*)(keepf + 10240);              // 1M bf16
  u16* w2b  = w1b + 1048576;
  u16* feat = w2b + 1048576;                      // MPAD*1024 bf16
  u16* hid1 = feat + (size_t)MPAD * 1024;
  u16* hid2 = feat;                               // reuse feat buffer

  float* out_scores = (float*)d_out;              // 10000
  float* out_ladj   = out_scores + NLINES;        // 40000
  float* out_juncs  = out_scores + 50000;         // 600
  float* out_jsc    = out_scores + 50600;         // 300

  k_prep<<<64, 256, 0, stream>>>(t_output, jloc, joffx, joffy);
  k_nms<<<64, 256, 0, stream>>>(jloc, jnms);
  k_topk<<<1, 1024, 0, stream>>>(jnms, joffx, joffy, juncs, out_juncs, out_jsc);
  k_match<<<40, 256, 0, stream>>>(juncs, t_lines, out_ladj, keepf);
  k_loi<<<256, 256, 0, stream>>>(t_features, t_fc1w, t_fc1b, loib);
  k_interp<<<NLINES, 256, 0, stream>>>(loib, out_ladj, feat);
  k_cvt<<<1024, 256, 0, stream>>>(t_w1, w1b, 1048576);
  k_cvt<<<1024, 256, 0, stream>>>(t_w2, w2b, 1048576);
  k_gemm<1><<<dim3(MPAD / 128, 8), 256, 0, stream>>>(feat, w1b, t_b1, hid1, MPAD, 1024, 1024);
  k_gemm<1><<<dim3(MPAD / 128, 8), 256, 0, stream>>>(hid1, w2b, t_b2, hid2, MPAD, 1024, 1024);
  k_head<<<2500, 256, 0, stream>>>(hid2, t_w3, t_b3, keepf, out_scores);
}

// Round 3
// 197.027 us; speedup vs baseline: 1.3766x; 1.1216x over previous
//
#include <hip/hip_runtime.h>
#include <stdint.h>

#define HW      16384   // 128*128
#define WIDTH   128
#define NTOPK   300
#define NLINES  10000
#define MPAD    10112   // 79*128

typedef unsigned short u16;
typedef unsigned int   u32;
typedef unsigned long long u64;
typedef __bf16 bf16x8 __attribute__((ext_vector_type(8)));
typedef float  f32x4  __attribute__((ext_vector_type(4)));

__device__ __forceinline__ u16 f2bf(float f) {
  u32 x = __builtin_bit_cast(u32, f);
  x += 0x7FFFu + ((x >> 16) & 1u);
  return (u16)(x >> 16);
}
__device__ __forceinline__ float bf2f(u32 u) {
  return __builtin_bit_cast(float, u << 16);
}
__device__ __forceinline__ void gload_lds16(void* lds, const void* g) {
  __builtin_amdgcn_global_load_lds(
      (const __attribute__((address_space(1))) void*)g,
      (__attribute__((address_space(3))) void*)lds, 16, 0, 0);
}

// ---------------- stage 1: jloc / joff ----------------
__global__ __launch_bounds__(256) void k_prep(const float* __restrict__ out9,
                                              float* __restrict__ jloc,
                                              float* __restrict__ joffx,
                                              float* __restrict__ joffy) {
  int i = blockIdx.x * 256 + threadIdx.x;
  if (i >= HW) return;
  float o5 = out9[5 * HW + i], o6 = out9[6 * HW + i];
  float o7 = out9[7 * HW + i], o8 = out9[8 * HW + i];
  jloc[i]  = 1.f / (1.f + expf(o5 - o6));        // softmax[1] == sigmoid(o6-o5)
  joffx[i] = 1.f / (1.f + expf(-o7)) - 0.5f;
  joffy[i] = 1.f / (1.f + expf(-o8)) - 0.5f;
}

// ---------------- stage 2: 3x3 NMS ----------------
__global__ __launch_bounds__(256) void k_nms(const float* __restrict__ jloc,
                                             float* __restrict__ jnms) {
  int i = blockIdx.x * 256 + threadIdx.x;
  if (i >= HW) return;
  int x = i & (WIDTH - 1), y = i >> 7;
  float a = jloc[i], m = a;
  for (int dy = -1; dy <= 1; ++dy) {
    int yy = y + dy;
    if (yy < 0 || yy >= WIDTH) continue;
    for (int dx = -1; dx <= 1; ++dx) {
      int xx = x + dx;
      if (xx < 0 || xx >= WIDTH) continue;
      m = fmaxf(m, jloc[yy * WIDTH + xx]);
    }
  }
  jnms[i] = (a == m) ? a : 0.f;
}

// ---------------- stage 3: top-300 via compact + bitonic sort ----------------
__global__ __launch_bounds__(1024) void k_topk(const float* __restrict__ jnms,
                                               const float* __restrict__ joffx,
                                               const float* __restrict__ joffy,
                                               float* __restrict__ juncs_ws,
                                               float* __restrict__ out_juncs,
                                               float* __restrict__ out_jsc) {
  __shared__ u64 keys[4096];
  __shared__ int cnt;
  int t = threadIdx.x;
  if (t == 0) cnt = 0;
  __syncthreads();
  for (int i = t; i < HW; i += 1024) {
    float v = jnms[i];
    if (v > 0.f) {
      int pos = atomicAdd(&cnt, 1);
      if (pos < 4096)
        keys[pos] = ((u64)__builtin_bit_cast(u32, v) << 32) | (u32)(0xFFFFFFFFu - (u32)i);
    }
  }
  __syncthreads();
  int c = cnt < 4096 ? cnt : 4096;
  for (int i = t; i < 4096; i += 1024)
    if (i >= c) keys[i] = 0ull;
  __syncthreads();
  // bitonic sort, descending
  for (int k = 2; k <= 4096; k <<= 1) {
    for (int j = k >> 1; j > 0; j >>= 1) {
      for (int u = t; u < 2048; u += 1024) {
        int i  = ((u & ~(j - 1)) << 1) | (u & (j - 1));
        int p  = i | j;
        u64 a = keys[i], b = keys[p];
        bool dir = (i & k) == 0;           // descending blocks
        if ((a < b) == dir) { keys[i] = b; keys[p] = a; }
      }
      __syncthreads();
    }
  }
  if (t < NTOPK) {
    u64 key = keys[t];
    u32 vb  = (u32)(key >> 32);
    int idx = (int)(0xFFFFFFFFu - (u32)(key & 0xFFFFFFFFu));
    float x = (float)(idx & (WIDTH - 1)) + joffx[idx] + 0.5f;
    float y = (float)(idx >> 7)          + joffy[idx] + 0.5f;
    juncs_ws[2 * t] = x; juncs_ws[2 * t + 1] = y;
    out_juncs[2 * t] = x; out_juncs[2 * t + 1] = y;
    out_jsc[t] = __builtin_bit_cast(float, vb);
  }
}

// ---------------- stage 4: endpoint matching ----------------
__global__ __launch_bounds__(256) void k_match(const float* __restrict__ juncs,
                                               const float* __restrict__ lines_pred,
                                               float* __restrict__ lines_adj,
                                               float* __restrict__ keepf) {
  __shared__ float jl[2 * NTOPK];
  for (int i = threadIdx.x; i < 2 * NTOPK; i += 256) jl[i] = juncs[i];
  __syncthreads();
  int l = blockIdx.x * 256 + threadIdx.x;
  if (l >= NLINES) return;
  float lx1 = lines_pred[l * 4 + 0], ly1 = lines_pred[l * 4 + 1];
  float lx2 = lines_pred[l * 4 + 2], ly2 = lines_pred[l * 4 + 3];
  float b1 = __builtin_inff(), b2 = __builtin_inff();
  int i1 = 0, i2 = 0;
  for (int j = 0; j < NTOPK; ++j) {
    float jx = jl[2 * j], jy = jl[2 * j + 1];
    // no-FMA: match numpy (a-b)^2 sum bitwise
    float dx = __fsub_rn(lx1, jx), dy = __fsub_rn(ly1, jy);
    float d  = __fadd_rn(__fmul_rn(dx, dx), __fmul_rn(dy, dy));
    if (d < b1) { b1 = d; i1 = j; }
    dx = __fsub_rn(lx2, jx); dy = __fsub_rn(ly2, jy);
    d  = __fadd_rn(__fmul_rn(dx, dx), __fmul_rn(dy, dy));
    if (d < b2) { b2 = d; i2 = j; }
  }
  int imin = i1 < i2 ? i1 : i2;
  int imax = i1 < i2 ? i2 : i1;
  lines_adj[l * 4 + 0] = jl[2 * imin];
  lines_adj[l * 4 + 1] = jl[2 * imin + 1];
  lines_adj[l * 4 + 2] = jl[2 * imax];
  lines_adj[l * 4 + 3] = jl[2 * imax + 1];
  keepf[l] = (imin < imax) ? 1.f : 0.f;
}

// ---------------- stage 5a: transpose features [256c][16384p] f32 -> featT [16384p][256c] bf16
__global__ __launch_bounds__(256) void k_transp(const float* __restrict__ features,
                                                u16* __restrict__ featT) {
  __shared__ float tile[64][65];     // stride 65: 2-way bank aliasing only (free)
  int t = threadIdx.x;
  int p0 = blockIdx.x * 64, c0 = blockIdx.y * 64;
#pragma unroll
  for (int i = 0; i < 4; ++i) {
    int lin = i * 256 + t;
    int c = lin >> 4, p4 = (lin & 15) * 4;
    float4 v = *(const float4*)&features[(size_t)(c0 + c) * HW + p0 + p4];
    tile[c][p4 + 0] = v.x; tile[c][p4 + 1] = v.y;
    tile[c][p4 + 2] = v.z; tile[c][p4 + 3] = v.w;
  }
  __syncthreads();
#pragma unroll
  for (int i = 0; i < 2; ++i) {
    int lin = i * 256 + t;
    int p = lin >> 3, c8 = (lin & 7) * 8;
    uint4 pk;
    pk.x = (u32)f2bf(tile[c8 + 0][p]) | ((u32)f2bf(tile[c8 + 1][p]) << 16);
    pk.y = (u32)f2bf(tile[c8 + 2][p]) | ((u32)f2bf(tile[c8 + 3][p]) << 16);
    pk.z = (u32)f2bf(tile[c8 + 4][p]) | ((u32)f2bf(tile[c8 + 5][p]) << 16);
    pk.w = (u32)f2bf(tile[c8 + 6][p]) | ((u32)f2bf(tile[c8 + 7][p]) << 16);
    *(uint4*)&featT[(size_t)(p0 + p) * 256 + c0 + c8] = pk;
  }
}

// ---------------- stage 6: line pooling -> feat bf16 (NLINES x 1024) ----------------
// loib: bf16 pixel-major [16384][128]. One block per line.
__device__ __forceinline__ void acc8(uint4 r, float wg, float* a) {
  a[0] += bf2f(r.x & 0xffffu) * wg; a[1] += bf2f(r.x >> 16) * wg;
  a[2] += bf2f(r.y & 0xffffu) * wg; a[3] += bf2f(r.y >> 16) * wg;
  a[4] += bf2f(r.z & 0xffffu) * wg; a[5] += bf2f(r.z >> 16) * wg;
  a[6] += bf2f(r.w & 0xffffu) * wg; a[7] += bf2f(r.w >> 16) * wg;
}
__global__ __launch_bounds__(256) void k_interp(const u16* __restrict__ loib,
                                                const float* __restrict__ lines_adj,
                                                u16* __restrict__ feat) {
  __shared__ u16 outb[8][128];   // [group s][channel]
  int l = blockIdx.x;
  int t = threadIdx.x;
  int w = t >> 6, lane = t & 63;
  int q = lane >> 4, chgrp = lane & 15;
  float ux = lines_adj[l * 4 + 0], uy = lines_adj[l * 4 + 1];
  float vx = lines_adj[l * 4 + 2], vy = lines_adj[l * 4 + 3];
#pragma unroll
  for (int it = 0; it < 2; ++it) {
    int s = it * 4 + w;
    int p = s * 4 + q;
    float tt = (float)p / 31.f;
    float px = ux * tt + vx * (1.f - tt) - 0.5f;
    float py = uy * tt + vy * (1.f - tt) - 0.5f;
    float px0 = fminf(fmaxf(floorf(px), 0.f), 127.f);
    float py0 = fminf(fmaxf(floorf(py), 0.f), 127.f);
    float px1 = fminf(px0 + 1.f, 127.f);
    float py1 = fminf(py0 + 1.f, 127.f);
    int ix0 = (int)px0, iy0 = (int)py0, ix1 = (int)px1, iy1 = (int)py1;
    float wy1 = py1 - py, wy0 = py - py0, wx1 = px1 - px, wx0 = px - px0;
    int co = chgrp * 8;
    uint4 v00 = *(const uint4*)&loib[(iy0 * WIDTH + ix0) * 128 + co];
    uint4 v10 = *(const uint4*)&loib[(iy1 * WIDTH + ix0) * 128 + co];
    uint4 v01 = *(const uint4*)&loib[(iy0 * WIDTH + ix1) * 128 + co];
    uint4 v11 = *(const uint4*)&loib[(iy1 * WIDTH + ix1) * 128 + co];
    float a[8];
#pragma unroll
    for (int c = 0; c < 8; ++c) a[c] = 0.f;
    acc8(v00, wy1 * wx1, a);
    acc8(v10, wy0 * wx1, a);
    acc8(v01, wy1 * wx0, a);
    acc8(v11, wy0 * wx0, a);
    // maxpool over q (4 points) via shuffles
#pragma unroll
    for (int c = 0; c < 8; ++c) {
      float v = fmaxf(a[c], __shfl_xor(a[c], 16, 64));
      v = fmaxf(v, __shfl_xor(v, 32, 64));
      a[c] = v;
    }
    if (q == 0) {
      uint4 pk;
      pk.x = (u32)f2bf(a[0]) | ((u32)f2bf(a[1]) << 16);
      pk.y = (u32)f2bf(a[2]) | ((u32)f2bf(a[3]) << 16);
      pk.z = (u32)f2bf(a[4]) | ((u32)f2bf(a[5]) << 16);
      pk.w = (u32)f2bf(a[6]) | ((u32)f2bf(a[7]) << 16);
      *(uint4*)&outb[s][co] = pk;
    }
  }
  __syncthreads();
  // transpose [s][ch] -> feat[l][ch*8+s], coalesced uint2 stores
  int ch = t >> 1, s0 = (t & 1) * 4;
  u16 e0 = outb[s0 + 0][ch], e1 = outb[s0 + 1][ch];
  u16 e2 = outb[s0 + 2][ch], e3 = outb[s0 + 3][ch];
  uint2 pk;
  pk.x = (u32)e0 | ((u32)e1 << 16);
  pk.y = (u32)e2 | ((u32)e3 << 16);
  *(uint2*)&feat[(size_t)l * 1024 + ch * 8 + s0] = pk;
}

// ---------------- f32 -> bf16 weight convert ----------------
__global__ __launch_bounds__(256) void k_cvt(const float* __restrict__ src,
                                             u16* __restrict__ dst, int n) {
  int i = (blockIdx.x * 256 + threadIdx.x) * 4;
  if (i >= n) return;
  float4 v = *(const float4*)&src[i];
  uint2 pk;
  pk.x = (u32)f2bf(v.x) | ((u32)f2bf(v.y) << 16);
  pk.y = (u32)f2bf(v.z) | ((u32)f2bf(v.w) << 16);
  *(uint2*)&dst[i] = pk;
}

// ---------------- m97-style bf16 GEMM:  C = act(A @ B^T + bias) ----------------
// A: M x K row-major bf16, B: N x K row-major bf16, C: M x N bf16.  M%128==0, N%128==0, K%32==0
template <int RELU>
__global__ __launch_bounds__(256) void k_gemm(const u16* __restrict__ A,
                                              const u16* __restrict__ B,
                                              const float* __restrict__ bias,
                                              u16* __restrict__ C,
                                              int M, int N, int K) {
  __shared__ u16 Alds[128 * 32];
  __shared__ u16 Blds[128 * 32];
  int t = threadIdx.x;
  int tm0 = blockIdx.x * 128;
  int tn0 = blockIdx.y * 128;
  int lane = t & 63, wid = t >> 6;
  int wr = wid >> 1, wc = wid & 1;
  f32x4 acc[4][4] = {};
  int arow = t >> 2, apos = (t & 3) * 8;   // staging: 4 threads/row, 8 bf16 each
  const u16* Abase = A + (size_t)tm0 * K;
  const u16* Bbase = B + (size_t)tn0 * K;
  int r = lane & 15, ks = (lane >> 4) * 8;
  for (int k0 = 0; k0 < K; k0 += 32) {
    gload_lds16(&Alds[(size_t)t * 8],         Abase + (size_t)arow * K + k0 + apos);
    gload_lds16(&Alds[(size_t)(t + 256) * 8], Abase + (size_t)(arow + 64) * K + k0 + apos);
    gload_lds16(&Blds[(size_t)t * 8],         Bbase + (size_t)arow * K + k0 + apos);
    gload_lds16(&Blds[(size_t)(t + 256) * 8], Bbase + (size_t)(arow + 64) * K + k0 + apos);
    __syncthreads();
    bf16x8 af[4], bfr[4];
#pragma unroll
    for (int i = 0; i < 4; ++i) {
      af[i]  = *(const bf16x8*)&Alds[(wr * 64 + i * 16 + r) * 32 + ks];
      bfr[i] = *(const bf16x8*)&Blds[(wc * 64 + i * 16 + r) * 32 + ks];
    }
#pragma unroll
    for (int mi = 0; mi < 4; ++mi)
#pragma unroll
      for (int ni = 0; ni < 4; ++ni)
        acc[mi][ni] = __builtin_amdgcn_mfma_f32_16x16x32_bf16(af[mi], bfr[ni], acc[mi][ni], 0, 0, 0);
    __syncthreads();
  }
  int rsub = (lane >> 4) * 4, csub = lane & 15;
#pragma unroll
  for (int mi = 0; mi < 4; ++mi) {
#pragma unroll
    for (int ni = 0; ni < 4; ++ni) {
      int col = tn0 + wc * 64 + ni * 16 + csub;
      float bv = bias[col];
#pragma unroll
      for (int j = 0; j < 4; ++j) {
        int row = tm0 + wr * 64 + mi * 16 + rsub + j;
        float v = acc[mi][ni][j] + bv;
        if (RELU) v = fmaxf(v, 0.f);
        C[(size_t)row * N + col] = f2bf(v);
      }
    }
  }
}

// ---------------- stage 9: logits + sigmoid * keep ----------------
__global__ __launch_bounds__(256) void k_head(const u16* __restrict__ hid2,
                                              const float* __restrict__ w3,
                                              const float* __restrict__ b3,
                                              const float* __restrict__ keepf,
                                              float* __restrict__ scores) {
  int wid = threadIdx.x >> 6, lane = threadIdx.x & 63;
  int l = blockIdx.x * 4 + wid;
  if (l >= NLINES) return;
  const u16* row = hid2 + (size_t)l * 1024;
  float acc = 0.f;
#pragma unroll
  for (int i = 0; i < 4; ++i) {
    int base = i * 256 + lane * 4;
    uint2 hv = *(const uint2*)&row[base];
    float4 wv = *(const float4*)&w3[base];
    acc += bf2f(hv.x & 0xffffu) * wv.x + bf2f(hv.x >> 16) * wv.y
         + bf2f(hv.y & 0xffffu) * wv.z + bf2f(hv.y >> 16) * wv.w;
  }
#pragma unroll
  for (int off = 32; off; off >>= 1) acc += __shfl_down(acc, off, 64);
  if (lane == 0) {
    float logit = acc + b3[0];
    float s = 1.f / (1.f + expf(-logit));
    scores[l] = s * keepf[l];
  }
}

extern "C" void kernel_launch(void* const* d_in, const int* in_sizes, int n_in,
                              void* d_out, int out_size, void* d_ws, size_t ws_size,
                              hipStream_t stream) {
  const float* t_output   = (const float*)d_in[0];
  const float* t_features = (const float*)d_in[1];
  const float* t_lines    = (const float*)d_in[2];
  const float* t_fc1w     = (const float*)d_in[3];
  const float* t_fc1b     = (const float*)d_in[4];
  const float* t_w1       = (const float*)d_in[5];
  const float* t_b1       = (const float*)d_in[6];
  const float* t_w2       = (const float*)d_in[7];
  const float* t_b2       = (const float*)d_in[8];
  const float* t_w3       = (const float*)d_in[9];
  const float* t_b3       = (const float*)d_in[10];

  // workspace layout (~50 MB)
  char* w = (char*)d_ws;
  u16*   loib  = (u16*)w;                         // 16384*128 bf16 = 4 MB
  float* jloc  = (float*)(w + 4194304);
  float* jnms  = jloc + HW;
  float* joffx = jnms + HW;
  float* joffy = joffx + HW;
  float* juncs = joffy + HW;                      // 600 f32 (pad 1024)
  float* keepf = juncs + 1024;                    // 10000 f32 (pad 10240)
  u16* fc1wb = (u16*)(keepf + 10240);             // 32768 bf16 (pad 32768)
  u16* w1b  = fc1wb + 32768;                      // 1M bf16
  u16* w2b  = w1b + 1048576;
  u16* feat = w2b + 1048576;                      // MPAD*1024 bf16
  u16* hid1 = feat + (size_t)MPAD * 1024;
  u16* hid2 = feat;                               // reuse feat buffer
  u16* featT = hid1;                              // alias: consumed before gemm1 writes hid1

  float* out_scores = (float*)d_out;              // 10000
  float* out_ladj   = out_scores + NLINES;        // 40000
  float* out_juncs  = out_scores + 50000;         // 600
  float* out_jsc    = out_scores + 50600;         // 300

  k_prep<<<64, 256, 0, stream>>>(t_output, jloc, joffx, joffy);
  k_nms<<<64, 256, 0, stream>>>(jloc, jnms);
  k_topk<<<1, 1024, 0, stream>>>(jnms, joffx, joffy, juncs, out_juncs, out_jsc);
  k_match<<<40, 256, 0, stream>>>(juncs, t_lines, out_ladj, keepf);
  k_cvt<<<32, 256, 0, stream>>>(t_fc1w, fc1wb, 32768);
  k_transp<<<dim3(256, 4), 256, 0, stream>>>(t_features, featT);
  k_gemm<0><<<dim3(128, 1), 256, 0, stream>>>(featT, fc1wb, t_fc1b, loib, HW, 128, 256);
  k_interp<<<NLINES, 256, 0, stream>>>(loib, out_ladj, feat);
  k_cvt<<<1024, 256, 0, stream>>>(t_w1, w1b, 1048576);
  k_cvt<<<1024, 256, 0, stream>>>(t_w2, w2b, 1048576);
  k_gemm<1><<<dim3(MPAD / 128, 8), 256, 0, stream>>>(feat, w1b, t_b1, hid1, MPAD, 1024, 1024);
  k_gemm<1><<<dim3(MPAD / 128, 8), 256, 0, stream>>>(hid1, w2b, t_b2, hid2, MPAD, 1024, 1024);
  k_head<<<2500, 256, 0, stream>>>(hid2, t_w3, t_b3, keepf, out_scores);
}

// Round 4
// 185.379 us; speedup vs baseline: 1.4631x; 1.0628x over previous
//
#include <hip/hip_runtime.h>
#include <stdint.h>

#define HW      16384   // 128*128
#define WIDTH   128
#define NTOPK   300
#define NLINES  10000
#define MPAD    10112   // 79*128

typedef unsigned short u16;
typedef unsigned int   u32;
typedef unsigned long long u64;
typedef __bf16 bf16x8 __attribute__((ext_vector_type(8)));
typedef float  f32x4  __attribute__((ext_vector_type(4)));

__device__ __forceinline__ u16 f2bf(float f) {
  u32 x = __builtin_bit_cast(u32, f);
  x += 0x7FFFu + ((x >> 16) & 1u);
  return (u16)(x >> 16);
}
__device__ __forceinline__ float bf2f(u32 u) {
  return __builtin_bit_cast(float, u << 16);
}
__device__ __forceinline__ void gload_lds16(void* lds, const void* g) {
  __builtin_amdgcn_global_load_lds(
      (const __attribute__((address_space(1))) void*)g,
      (__attribute__((address_space(3))) void*)lds, 16, 0, 0);
}

// ---------------- stage 1: jloc / joff ----------------
__global__ __launch_bounds__(256) void k_prep(const float* __restrict__ out9,
                                              float* __restrict__ jloc,
                                              float* __restrict__ joffx,
                                              float* __restrict__ joffy) {
  int i = blockIdx.x * 256 + threadIdx.x;
  if (i >= HW) return;
  float o5 = out9[5 * HW + i], o6 = out9[6 * HW + i];
  float o7 = out9[7 * HW + i], o8 = out9[8 * HW + i];
  jloc[i]  = 1.f / (1.f + expf(o5 - o6));        // softmax[1] == sigmoid(o6-o5)
  joffx[i] = 1.f / (1.f + expf(-o7)) - 0.5f;
  joffy[i] = 1.f / (1.f + expf(-o8)) - 0.5f;
}

// ---------------- stage 2: 3x3 NMS ----------------
__global__ __launch_bounds__(256) void k_nms(const float* __restrict__ jloc,
                                             float* __restrict__ jnms) {
  int i = blockIdx.x * 256 + threadIdx.x;
  if (i >= HW) return;
  int x = i & (WIDTH - 1), y = i >> 7;
  float a = jloc[i], m = a;
  for (int dy = -1; dy <= 1; ++dy) {
    int yy = y + dy;
    if (yy < 0 || yy >= WIDTH) continue;
    for (int dx = -1; dx <= 1; ++dx) {
      int xx = x + dx;
      if (xx < 0 || xx >= WIDTH) continue;
      m = fmaxf(m, jloc[yy * WIDTH + xx]);
    }
  }
  jnms[i] = (a == m) ? a : 0.f;
}

// ---------------- stage 3: top-300 via compact + bitonic sort ----------------
__global__ __launch_bounds__(1024) void k_topk(const float* __restrict__ jnms,
                                               const float* __restrict__ joffx,
                                               const float* __restrict__ joffy,
                                               float* __restrict__ juncs_ws,
                                               float* __restrict__ out_juncs,
                                               float* __restrict__ out_jsc) {
  __shared__ u64 keys[4096];
  __shared__ int cnt;
  int t = threadIdx.x;
  if (t == 0) cnt = 0;
  __syncthreads();
  for (int i = t; i < HW; i += 1024) {
    float v = jnms[i];
    if (v > 0.f) {
      int pos = atomicAdd(&cnt, 1);
      if (pos < 4096)
        keys[pos] = ((u64)__builtin_bit_cast(u32, v) << 32) | (u32)(0xFFFFFFFFu - (u32)i);
    }
  }
  __syncthreads();
  int c = cnt < 4096 ? cnt : 4096;
  for (int i = t; i < 4096; i += 1024)
    if (i >= c) keys[i] = 0ull;
  __syncthreads();
  // bitonic sort, descending
  for (int k = 2; k <= 4096; k <<= 1) {
    for (int j = k >> 1; j > 0; j >>= 1) {
      for (int u = t; u < 2048; u += 1024) {
        int i  = ((u & ~(j - 1)) << 1) | (u & (j - 1));
        int p  = i | j;
        u64 a = keys[i], b = keys[p];
        bool dir = (i & k) == 0;           // descending blocks
        if ((a < b) == dir) { keys[i] = b; keys[p] = a; }
      }
      __syncthreads();
    }
  }
  if (t < NTOPK) {
    u64 key = keys[t];
    u32 vb  = (u32)(key >> 32);
    int idx = (int)(0xFFFFFFFFu - (u32)(key & 0xFFFFFFFFu));
    float x = (float)(idx & (WIDTH - 1)) + joffx[idx] + 0.5f;
    float y = (float)(idx >> 7)          + joffy[idx] + 0.5f;
    juncs_ws[2 * t] = x; juncs_ws[2 * t + 1] = y;
    out_juncs[2 * t] = x; out_juncs[2 * t + 1] = y;
    out_jsc[t] = __builtin_bit_cast(float, vb);
  }
}

// ---------------- stage 4: endpoint matching ----------------
__global__ __launch_bounds__(256) void k_match(const float* __restrict__ juncs,
                                               const float* __restrict__ lines_pred,
                                               float* __restrict__ lines_adj,
                                               float* __restrict__ keepf) {
  __shared__ float jl[2 * NTOPK];
  for (int i = threadIdx.x; i < 2 * NTOPK; i += 256) jl[i] = juncs[i];
  __syncthreads();
  int l = blockIdx.x * 256 + threadIdx.x;
  if (l >= NLINES) return;
  float lx1 = lines_pred[l * 4 + 0], ly1 = lines_pred[l * 4 + 1];
  float lx2 = lines_pred[l * 4 + 2], ly2 = lines_pred[l * 4 + 3];
  float b1 = __builtin_inff(), b2 = __builtin_inff();
  int i1 = 0, i2 = 0;
  for (int j = 0; j < NTOPK; ++j) {
    float jx = jl[2 * j], jy = jl[2 * j + 1];
    // no-FMA: match numpy (a-b)^2 sum bitwise
    float dx = __fsub_rn(lx1, jx), dy = __fsub_rn(ly1, jy);
    float d  = __fadd_rn(__fmul_rn(dx, dx), __fmul_rn(dy, dy));
    if (d < b1) { b1 = d; i1 = j; }
    dx = __fsub_rn(lx2, jx); dy = __fsub_rn(ly2, jy);
    d  = __fadd_rn(__fmul_rn(dx, dx), __fmul_rn(dy, dy));
    if (d < b2) { b2 = d; i2 = j; }
  }
  int imin = i1 < i2 ? i1 : i2;
  int imax = i1 < i2 ? i2 : i1;
  lines_adj[l * 4 + 0] = jl[2 * imin];
  lines_adj[l * 4 + 1] = jl[2 * imin + 1];
  lines_adj[l * 4 + 2] = jl[2 * imax];
  lines_adj[l * 4 + 3] = jl[2 * imax + 1];
  keepf[l] = (imin < imax) ? 1.f : 0.f;
}

// ---------------- stage 5a: transpose features [256c][16384p] f32 -> featT [16384p][256c] bf16
__global__ __launch_bounds__(256) void k_transp(const float* __restrict__ features,
                                                u16* __restrict__ featT) {
  __shared__ float tile[64][65];     // stride 65: 2-way bank aliasing only (free)
  int t = threadIdx.x;
  int p0 = blockIdx.x * 64, c0 = blockIdx.y * 64;
#pragma unroll
  for (int i = 0; i < 4; ++i) {
    int lin = i * 256 + t;
    int c = lin >> 4, p4 = (lin & 15) * 4;
    float4 v = *(const float4*)&features[(size_t)(c0 + c) * HW + p0 + p4];
    tile[c][p4 + 0] = v.x; tile[c][p4 + 1] = v.y;
    tile[c][p4 + 2] = v.z; tile[c][p4 + 3] = v.w;
  }
  __syncthreads();
#pragma unroll
  for (int i = 0; i < 2; ++i) {
    int lin = i * 256 + t;
    int p = lin >> 3, c8 = (lin & 7) * 8;
    uint4 pk;
    pk.x = (u32)f2bf(tile[c8 + 0][p]) | ((u32)f2bf(tile[c8 + 1][p]) << 16);
    pk.y = (u32)f2bf(tile[c8 + 2][p]) | ((u32)f2bf(tile[c8 + 3][p]) << 16);
    pk.z = (u32)f2bf(tile[c8 + 4][p]) | ((u32)f2bf(tile[c8 + 5][p]) << 16);
    pk.w = (u32)f2bf(tile[c8 + 6][p]) | ((u32)f2bf(tile[c8 + 7][p]) << 16);
    *(uint4*)&featT[(size_t)(p0 + p) * 256 + c0 + c8] = pk;
  }
}

// ---------------- stage 6: line pooling -> feat bf16 (NLINES x 1024) ----------------
// loib: bf16 pixel-major [16384][128]. One block per line.
__device__ __forceinline__ void acc8(uint4 r, float wg, float* a) {
  a[0] += bf2f(r.x & 0xffffu) * wg; a[1] += bf2f(r.x >> 16) * wg;
  a[2] += bf2f(r.y & 0xffffu) * wg; a[3] += bf2f(r.y >> 16) * wg;
  a[4] += bf2f(r.z & 0xffffu) * wg; a[5] += bf2f(r.z >> 16) * wg;
  a[6] += bf2f(r.w & 0xffffu) * wg; a[7] += bf2f(r.w >> 16) * wg;
}
__global__ __launch_bounds__(256) void k_interp(const u16* __restrict__ loib,
                                                const float* __restrict__ lines_adj,
                                                u16* __restrict__ feat) {
  __shared__ u16 outb[8][128];   // [group s][channel]
  int l = blockIdx.x;
  int t = threadIdx.x;
  int w = t >> 6, lane = t & 63;
  int q = lane >> 4, chgrp = lane & 15;
  float ux = lines_adj[l * 4 + 0], uy = lines_adj[l * 4 + 1];
  float vx = lines_adj[l * 4 + 2], vy = lines_adj[l * 4 + 3];
#pragma unroll
  for (int it = 0; it < 2; ++it) {
    int s = it * 4 + w;
    int p = s * 4 + q;
    float tt = (float)p / 31.f;
    float px = ux * tt + vx * (1.f - tt) - 0.5f;
    float py = uy * tt + vy * (1.f - tt) - 0.5f;
    float px0 = fminf(fmaxf(floorf(px), 0.f), 127.f);
    float py0 = fminf(fmaxf(floorf(py), 0.f), 127.f);
    float px1 = fminf(px0 + 1.f, 127.f);
    float py1 = fminf(py0 + 1.f, 127.f);
    int ix0 = (int)px0, iy0 = (int)py0, ix1 = (int)px1, iy1 = (int)py1;
    float wy1 = py1 - py, wy0 = py - py0, wx1 = px1 - px, wx0 = px - px0;
    int co = chgrp * 8;
    uint4 v00 = *(const uint4*)&loib[(iy0 * WIDTH + ix0) * 128 + co];
    uint4 v10 = *(const uint4*)&loib[(iy1 * WIDTH + ix0) * 128 + co];
    uint4 v01 = *(const uint4*)&loib[(iy0 * WIDTH + ix1) * 128 + co];
    uint4 v11 = *(const uint4*)&loib[(iy1 * WIDTH + ix1) * 128 + co];
    float a[8];
#pragma unroll
    for (int c = 0; c < 8; ++c) a[c] = 0.f;
    acc8(v00, wy1 * wx1, a);
    acc8(v10, wy0 * wx1, a);
    acc8(v01, wy1 * wx0, a);
    acc8(v11, wy0 * wx0, a);
    // maxpool over q (4 points) via shuffles
#pragma unroll
    for (int c = 0; c < 8; ++c) {
      float v = fmaxf(a[c], __shfl_xor(a[c], 16, 64));
      v = fmaxf(v, __shfl_xor(v, 32, 64));
      a[c] = v;
    }
    if (q == 0) {
      uint4 pk;
      pk.x = (u32)f2bf(a[0]) | ((u32)f2bf(a[1]) << 16);
      pk.y = (u32)f2bf(a[2]) | ((u32)f2bf(a[3]) << 16);
      pk.z = (u32)f2bf(a[4]) | ((u32)f2bf(a[5]) << 16);
      pk.w = (u32)f2bf(a[6]) | ((u32)f2bf(a[7]) << 16);
      *(uint4*)&outb[s][co] = pk;
    }
  }
  __syncthreads();
  // transpose [s][ch] -> feat[l][ch*8+s], coalesced uint2 stores
  int ch = t >> 1, s0 = (t & 1) * 4;
  u16 e0 = outb[s0 + 0][ch], e1 = outb[s0 + 1][ch];
  u16 e2 = outb[s0 + 2][ch], e3 = outb[s0 + 3][ch];
  uint2 pk;
  pk.x = (u32)e0 | ((u32)e1 << 16);
  pk.y = (u32)e2 | ((u32)e3 << 16);
  *(uint2*)&feat[(size_t)l * 1024 + ch * 8 + s0] = pk;
}

// ---------------- f32 -> bf16 weight convert ----------------
__global__ __launch_bounds__(256) void k_cvt(const float* __restrict__ src,
                                             u16* __restrict__ dst, int n) {
  int i = (blockIdx.x * 256 + threadIdx.x) * 4;
  if (i >= n) return;
  float4 v = *(const float4*)&src[i];
  uint2 pk;
  pk.x = (u32)f2bf(v.x) | ((u32)f2bf(v.y) << 16);
  pk.y = (u32)f2bf(v.z) | ((u32)f2bf(v.w) << 16);
  *(uint2*)&dst[i] = pk;
}

// ---------------- m97-style bf16 GEMM:  C = act(A @ B^T + bias) ----------------
// A: M x K row-major bf16, B: N x K row-major bf16, C: M x N bf16.  M%128==0, N%128==0, K%32==0
// XCD-aware bijective swizzle (T1): requires (gridDim.x*gridDim.y) % 8 == 0.
// Within each XCD chunk, B-column tiles vary fastest -> per-XCD working set =
// ~11 A-row-tiles + whole B, L2-resident.
template <int RELU>
__global__ __launch_bounds__(256) void k_gemm(const u16* __restrict__ A,
                                              const u16* __restrict__ B,
                                              const float* __restrict__ bias,
                                              u16* __restrict__ C,
                                              int M, int N, int K) {
  __shared__ u16 Alds[128 * 32];
  __shared__ u16 Blds[128 * 32];
  int nwg = gridDim.x * gridDim.y;
  int bid = blockIdx.y * gridDim.x + blockIdx.x;   // HW linear dispatch id
  int cpx = nwg >> 3;                              // blocks per XCD
  int key = (bid & 7) * cpx + (bid >> 3);          // bijective when nwg%8==0
  int bx = key / gridDim.y;
  int by = key % gridDim.y;
  int t = threadIdx.x;
  int tm0 = bx * 128;
  int tn0 = by * 128;
  int lane = t & 63, wid = t >> 6;
  int wr = wid >> 1, wc = wid & 1;
  f32x4 acc[4][4] = {};
  int arow = t >> 2, apos = (t & 3) * 8;   // staging: 4 threads/row, 8 bf16 each
  const u16* Abase = A + (size_t)tm0 * K;
  const u16* Bbase = B + (size_t)tn0 * K;
  int r = lane & 15, ks = (lane >> 4) * 8;
  for (int k0 = 0; k0 < K; k0 += 32) {
    gload_lds16(&Alds[(size_t)t * 8],         Abase + (size_t)arow * K + k0 + apos);
    gload_lds16(&Alds[(size_t)(t + 256) * 8], Abase + (size_t)(arow + 64) * K + k0 + apos);
    gload_lds16(&Blds[(size_t)t * 8],         Bbase + (size_t)arow * K + k0 + apos);
    gload_lds16(&Blds[(size_t)(t + 256) * 8], Bbase + (size_t)(arow + 64) * K + k0 + apos);
    __syncthreads();
    bf16x8 af[4], bfr[4];
#pragma unroll
    for (int i = 0; i < 4; ++i) {
      af[i]  = *(const bf16x8*)&Alds[(wr * 64 + i * 16 + r) * 32 + ks];
      bfr[i] = *(const bf16x8*)&Blds[(wc * 64 + i * 16 + r) * 32 + ks];
    }
#pragma unroll
    for (int mi = 0; mi < 4; ++mi)
#pragma unroll
      for (int ni = 0; ni < 4; ++ni)
        acc[mi][ni] = __builtin_amdgcn_mfma_f32_16x16x32_bf16(af[mi], bfr[ni], acc[mi][ni], 0, 0, 0);
    __syncthreads();
  }
  int rsub = (lane >> 4) * 4, csub = lane & 15;
#pragma unroll
  for (int mi = 0; mi < 4; ++mi) {
#pragma unroll
    for (int ni = 0; ni < 4; ++ni) {
      int col = tn0 + wc * 64 + ni * 16 + csub;
      float bv = bias[col];
#pragma unroll
      for (int j = 0; j < 4; ++j) {
        int row = tm0 + wr * 64 + mi * 16 + rsub + j;
        float v = acc[mi][ni][j] + bv;
        if (RELU) v = fmaxf(v, 0.f);
        C[(size_t)row * N + col] = f2bf(v);
      }
    }
  }
}

// ---------------- stage 9: logits + sigmoid * keep ----------------
__global__ __launch_bounds__(256) void k_head(const u16* __restrict__ hid2,
                                              const float* __restrict__ w3,
                                              const float* __restrict__ b3,
                                              const float* __restrict__ keepf,
                                              float* __restrict__ scores) {
  int wid = threadIdx.x >> 6, lane = threadIdx.x & 63;
  int l = blockIdx.x * 4 + wid;
  if (l >= NLINES) return;
  const u16* row = hid2 + (size_t)l * 1024;
  float acc = 0.f;
#pragma unroll
  for (int i = 0; i < 4; ++i) {
    int base = i * 256 + lane * 4;
    uint2 hv = *(const uint2*)&row[base];
    float4 wv = *(const float4*)&w3[base];
    acc += bf2f(hv.x & 0xffffu) * wv.x + bf2f(hv.x >> 16) * wv.y
         + bf2f(hv.y & 0xffffu) * wv.z + bf2f(hv.y >> 16) * wv.w;
  }
#pragma unroll
  for (int off = 32; off; off >>= 1) acc += __shfl_down(acc, off, 64);
  if (lane == 0) {
    float logit = acc + b3[0];
    float s = 1.f / (1.f + expf(-logit));
    scores[l] = s * keepf[l];
  }
}

extern "C" void kernel_launch(void* const* d_in, const int* in_sizes, int n_in,
                              void* d_out, int out_size, void* d_ws, size_t ws_size,
                              hipStream_t stream) {
  const float* t_output   = (const float*)d_in[0];
  const float* t_features = (const float*)d_in[1];
  const float* t_lines    = (const float*)d_in[2];
  const float* t_fc1w     = (const float*)d_in[3];
  const float* t_fc1b     = (const float*)d_in[4];
  const float* t_w1       = (const float*)d_in[5];
  const float* t_b1       = (const float*)d_in[6];
  const float* t_w2       = (const float*)d_in[7];
  const float* t_b2       = (const float*)d_in[8];
  const float* t_w3       = (const float*)d_in[9];
  const float* t_b3       = (const float*)d_in[10];

  // workspace layout (~50 MB)
  char* w = (char*)d_ws;
  u16*   loib  = (u16*)w;                         // 16384*128 bf16 = 4 MB
  float* jloc  = (float*)(w + 4194304);
  float* jnms  = jloc + HW;
  float* joffx = jnms + HW;
  float* joffy = joffx + HW;
  float* juncs = joffy + HW;                      // 600 f32 (pad 1024)
  float* keepf = juncs + 1024;                    // 10000 f32 (pad 10240)
  u16* fc1wb = (u16*)(keepf + 10240);             // 32768 bf16 (pad 32768)
  u16* w1b  = fc1wb + 32768;                      // 1M bf16
  u16* w2b  = w1b + 1048576;
  u16* feat = w2b + 1048576;                      // MPAD*1024 bf16
  u16* hid1 = feat + (size_t)MPAD * 1024;
  u16* hid2 = feat;                               // reuse feat buffer
  u16* featT = hid1;                              // alias: consumed before gemm1 writes hid1

  float* out_scores = (float*)d_out;              // 10000
  float* out_ladj   = out_scores + NLINES;        // 40000
  float* out_juncs  = out_scores + 50000;         // 600
  float* out_jsc    = out_scores + 50600;         // 300

  k_prep<<<64, 256, 0, stream>>>(t_output, jloc, joffx, joffy);
  k_nms<<<64, 256, 0, stream>>>(jloc, jnms);
  k_topk<<<1, 1024, 0, stream>>>(jnms, joffx, joffy, juncs, out_juncs, out_jsc);
  k_match<<<40, 256, 0, stream>>>(juncs, t_lines, out_ladj, keepf);
  k_cvt<<<32, 256, 0, stream>>>(t_fc1w, fc1wb, 32768);
  k_transp<<<dim3(256, 4), 256, 0, stream>>>(t_features, featT);
  k_gemm<0><<<dim3(128, 1), 256, 0, stream>>>(featT, fc1wb, t_fc1b, loib, HW, 128, 256);
  k_interp<<<NLINES, 256, 0, stream>>>(loib, out_ladj, feat);
  k_cvt<<<1024, 256, 0, stream>>>(t_w1, w1b, 1048576);
  k_cvt<<<1024, 256, 0, stream>>>(t_w2, w2b, 1048576);
  k_gemm<1><<<dim3(MPAD / 128, 8), 256, 0, stream>>>(feat, w1b, t_b1, hid1, MPAD, 1024, 1024);
  k_gemm<1><<<dim3(MPAD / 128, 8), 256, 0, stream>>>(hid1, w2b, t_b2, hid2, MPAD, 1024, 1024);
  k_head<<<2500, 256, 0, stream>>>(hid2, t_w3, t_b3, keepf, out_scores);
}

// Round 5
// 158.143 us; speedup vs baseline: 1.7151x; 1.1722x over previous
//
#include <hip/hip_runtime.h>
#include <stdint.h>

#define HW      16384   // 128*128
#define WIDTH   128
#define NTOPK   300
#define NLINES  10000
#define MPAD    10112   // 79*128

typedef unsigned short u16;
typedef unsigned int   u32;
typedef unsigned long long u64;
typedef __bf16 bf16x8 __attribute__((ext_vector_type(8)));
typedef float  f32x4  __attribute__((ext_vector_type(4)));

__device__ __forceinline__ u16 f2bf(float f) {
  u32 x = __builtin_bit_cast(u32, f);
  x += 0x7FFFu + ((x >> 16) & 1u);
  return (u16)(x >> 16);
}
__device__ __forceinline__ float bf2f(u32 u) {
  return __builtin_bit_cast(float, u << 16);
}
__device__ __forceinline__ void gload_lds16(void* lds, const void* g) {
  __builtin_amdgcn_global_load_lds(
      (const __attribute__((address_space(1))) void*)g,
      (__attribute__((address_space(3))) void*)lds, 16, 0, 0);
}

// ---------------- stage 1+2 fused: NMS directly from out9 ----------------
// jloc = sigmoid(o6-o5) computed per tile+halo in LDS; 3x3 NMS with -inf pad.
__global__ __launch_bounds__(256) void k_nms(const float* __restrict__ out9,
                                             float* __restrict__ jnms) {
  __shared__ float jl[18][18];
  int t = threadIdx.x;
  int gx0 = blockIdx.x * 16 - 1, gy0 = blockIdx.y * 16 - 1;
  for (int lin = t; lin < 324; lin += 256) {
    int lx = lin % 18, ly = lin / 18;
    int gx = gx0 + lx, gy = gy0 + ly;
    float v = -__builtin_inff();
    if (gx >= 0 && gx < WIDTH && gy >= 0 && gy < WIDTH) {
      int i = gy * WIDTH + gx;
      v = 1.f / (1.f + expf(out9[5 * HW + i] - out9[6 * HW + i]));
    }
    jl[ly][lx] = v;
  }
  __syncthreads();
  int tx = t & 15, ty = t >> 4;
  float a = jl[ty + 1][tx + 1], m = a;
#pragma unroll
  for (int dy = 0; dy < 3; ++dy)
#pragma unroll
    for (int dx = 0; dx < 3; ++dx)
      m = fmaxf(m, jl[ty + dy][tx + dx]);
  int gx = blockIdx.x * 16 + tx, gy = blockIdx.y * 16 + ty;
  jnms[gy * WIDTH + gx] = (a == m) ? a : 0.f;
}

// ---------------- stage 3: top-300 via compact + bitonic sort ----------------
// joff sigmoid computed on demand for the 300 winners only.
__global__ __launch_bounds__(1024) void k_topk(const float* __restrict__ jnms,
                                               const float* __restrict__ out9,
                                               float* __restrict__ juncs_ws,
                                               float* __restrict__ out_juncs,
                                               float* __restrict__ out_jsc) {
  __shared__ u64 keys[4096];
  __shared__ int cnt;
  int t = threadIdx.x;
  if (t == 0) cnt = 0;
  __syncthreads();
  for (int i = t; i < HW; i += 1024) {
    float v = jnms[i];
    if (v > 0.f) {
      int pos = atomicAdd(&cnt, 1);
      if (pos < 4096)
        keys[pos] = ((u64)__builtin_bit_cast(u32, v) << 32) | (u32)(0xFFFFFFFFu - (u32)i);
    }
  }
  __syncthreads();
  int c = cnt < 4096 ? cnt : 4096;
  int n = (c <= 2048) ? 2048 : 4096;   // expected cnt ~1850; exact fallback kept
  for (int i = t; i < n; i += 1024)
    if (i >= c) keys[i] = 0ull;
  __syncthreads();
  // bitonic sort, descending
  for (int k = 2; k <= n; k <<= 1) {
    for (int j = k >> 1; j > 0; j >>= 1) {
      for (int u = t; u < (n >> 1); u += 1024) {
        int i  = ((u & ~(j - 1)) << 1) | (u & (j - 1));
        int p  = i | j;
        u64 a = keys[i], b = keys[p];
        bool dir = (i & k) == 0;           // descending blocks
        if ((a < b) == dir) { keys[i] = b; keys[p] = a; }
      }
      __syncthreads();
    }
  }
  if (t < NTOPK) {
    u64 key = keys[t];
    u32 vb  = (u32)(key >> 32);
    int idx = (int)(0xFFFFFFFFu - (u32)(key & 0xFFFFFFFFu));
    float ox = 1.f / (1.f + expf(-out9[7 * HW + idx])) - 0.5f;
    float oy = 1.f / (1.f + expf(-out9[8 * HW + idx])) - 0.5f;
    float x = (float)(idx & (WIDTH - 1)) + ox + 0.5f;
    float y = (float)(idx >> 7)          + oy + 0.5f;
    juncs_ws[2 * t] = x; juncs_ws[2 * t + 1] = y;
    out_juncs[2 * t] = x; out_juncs[2 * t + 1] = y;
    out_jsc[t] = __builtin_bit_cast(float, vb);
  }
}

// ---------------- stage 4: endpoint matching, wave-per-line ----------------
__global__ __launch_bounds__(256) void k_match(const float* __restrict__ juncs,
                                               const float* __restrict__ lines_pred,
                                               float* __restrict__ lines_adj,
                                               float* __restrict__ keepf) {
  __shared__ float jl[2 * NTOPK];
  int t = threadIdx.x;
  for (int i = t; i < 2 * NTOPK; i += 256) jl[i] = juncs[i];
  __syncthreads();
  int wid = t >> 6, lane = t & 63;
  int l = blockIdx.x * 4 + wid;
  if (l >= NLINES) return;
  float lx1 = lines_pred[l * 4 + 0], ly1 = lines_pred[l * 4 + 1];
  float lx2 = lines_pred[l * 4 + 2], ly2 = lines_pred[l * 4 + 3];
  float b1 = __builtin_inff(), b2 = __builtin_inff();
  int i1 = 0, i2 = 0;
  for (int j = lane; j < NTOPK; j += 64) {
    float jx = jl[2 * j], jy = jl[2 * j + 1];
    // no-FMA: match numpy (a-b)^2 sum bitwise
    float dx = __fsub_rn(lx1, jx), dy = __fsub_rn(ly1, jy);
    float d  = __fadd_rn(__fmul_rn(dx, dx), __fmul_rn(dy, dy));
    if (d < b1) { b1 = d; i1 = j; }
    dx = __fsub_rn(lx2, jx); dy = __fsub_rn(ly2, jy);
    d  = __fadd_rn(__fmul_rn(dx, dx), __fmul_rn(dy, dy));
    if (d < b2) { b2 = d; i2 = j; }
  }
  // cross-lane lexicographic (d, idx) min == numpy argmin (first occurrence)
#pragma unroll
  for (int off = 1; off < 64; off <<= 1) {
    float d_o = __shfl_xor(b1, off, 64); int i_o = __shfl_xor(i1, off, 64);
    if (d_o < b1 || (d_o == b1 && i_o < i1)) { b1 = d_o; i1 = i_o; }
    d_o = __shfl_xor(b2, off, 64); i_o = __shfl_xor(i2, off, 64);
    if (d_o < b2 || (d_o == b2 && i_o < i2)) { b2 = d_o; i2 = i_o; }
  }
  if (lane == 0) {
    int imin = i1 < i2 ? i1 : i2;
    int imax = i1 < i2 ? i2 : i1;
    lines_adj[l * 4 + 0] = jl[2 * imin];
    lines_adj[l * 4 + 1] = jl[2 * imin + 1];
    lines_adj[l * 4 + 2] = jl[2 * imax];
    lines_adj[l * 4 + 3] = jl[2 * imax + 1];
    keepf[l] = (imin < imax) ? 1.f : 0.f;
  }
}

// ---------------- stage 5a: transpose features [256c][16384p] f32 -> featT [16384p][256c] bf16
__global__ __launch_bounds__(256) void k_transp(const float* __restrict__ features,
                                                u16* __restrict__ featT) {
  __shared__ float tile[64][65];     // stride 65: 2-way bank aliasing only (free)
  int t = threadIdx.x;
  int p0 = blockIdx.x * 64, c0 = blockIdx.y * 64;
#pragma unroll
  for (int i = 0; i < 4; ++i) {
    int lin = i * 256 + t;
    int c = lin >> 4, p4 = (lin & 15) * 4;
    float4 v = *(const float4*)&features[(size_t)(c0 + c) * HW + p0 + p4];
    tile[c][p4 + 0] = v.x; tile[c][p4 + 1] = v.y;
    tile[c][p4 + 2] = v.z; tile[c][p4 + 3] = v.w;
  }
  __syncthreads();
#pragma unroll
  for (int i = 0; i < 2; ++i) {
    int lin = i * 256 + t;
    int p = lin >> 3, c8 = (lin & 7) * 8;
    uint4 pk;
    pk.x = (u32)f2bf(tile[c8 + 0][p]) | ((u32)f2bf(tile[c8 + 1][p]) << 16);
    pk.y = (u32)f2bf(tile[c8 + 2][p]) | ((u32)f2bf(tile[c8 + 3][p]) << 16);
    pk.z = (u32)f2bf(tile[c8 + 4][p]) | ((u32)f2bf(tile[c8 + 5][p]) << 16);
    pk.w = (u32)f2bf(tile[c8 + 6][p]) | ((u32)f2bf(tile[c8 + 7][p]) << 16);
    *(uint4*)&featT[(size_t)(p0 + p) * 256 + c0 + c8] = pk;
  }
}

// ---------------- stage 6: line pooling -> feat bf16 (NLINES x 1024) ----------------
__device__ __forceinline__ void acc8(uint4 r, float wg, float* a) {
  a[0] += bf2f(r.x & 0xffffu) * wg; a[1] += bf2f(r.x >> 16) * wg;
  a[2] += bf2f(r.y & 0xffffu) * wg; a[3] += bf2f(r.y >> 16) * wg;
  a[4] += bf2f(r.z & 0xffffu) * wg; a[5] += bf2f(r.z >> 16) * wg;
  a[6] += bf2f(r.w & 0xffffu) * wg; a[7] += bf2f(r.w >> 16) * wg;
}
__global__ __launch_bounds__(256) void k_interp(const u16* __restrict__ loib,
                                                const float* __restrict__ lines_adj,
                                                u16* __restrict__ feat) {
  __shared__ u16 outb[8][128];   // [group s][channel]
  int l = blockIdx.x;
  int t = threadIdx.x;
  int w = t >> 6, lane = t & 63;
  int q = lane >> 4, chgrp = lane & 15;
  float ux = lines_adj[l * 4 + 0], uy = lines_adj[l * 4 + 1];
  float vx = lines_adj[l * 4 + 2], vy = lines_adj[l * 4 + 3];
#pragma unroll
  for (int it = 0; it < 2; ++it) {
    int s = it * 4 + w;
    int p = s * 4 + q;
    float tt = (float)p / 31.f;
    float px = ux * tt + vx * (1.f - tt) - 0.5f;
    float py = uy * tt + vy * (1.f - tt) - 0.5f;
    float px0 = fminf(fmaxf(floorf(px), 0.f), 127.f);
    float py0 = fminf(fmaxf(floorf(py), 0.f), 127.f);
    float px1 = fminf(px0 + 1.f, 127.f);
    float py1 = fminf(py0 + 1.f, 127.f);
    int ix0 = (int)px0, iy0 = (int)py0, ix1 = (int)px1, iy1 = (int)py1;
    float wy1 = py1 - py, wy0 = py - py0, wx1 = px1 - px, wx0 = px - px0;
    int co = chgrp * 8;
    uint4 v00 = *(const uint4*)&loib[(iy0 * WIDTH + ix0) * 128 + co];
    uint4 v10 = *(const uint4*)&loib[(iy1 * WIDTH + ix0) * 128 + co];
    uint4 v01 = *(const uint4*)&loib[(iy0 * WIDTH + ix1) * 128 + co];
    uint4 v11 = *(const uint4*)&loib[(iy1 * WIDTH + ix1) * 128 + co];
    float a[8];
#pragma unroll
    for (int c = 0; c < 8; ++c) a[c] = 0.f;
    acc8(v00, wy1 * wx1, a);
    acc8(v10, wy0 * wx1, a);
    acc8(v01, wy1 * wx0, a);
    acc8(v11, wy0 * wx0, a);
#pragma unroll
    for (int c = 0; c < 8; ++c) {
      float v = fmaxf(a[c], __shfl_xor(a[c], 16, 64));
      v = fmaxf(v, __shfl_xor(v, 32, 64));
      a[c] = v;
    }
    if (q == 0) {
      uint4 pk;
      pk.x = (u32)f2bf(a[0]) | ((u32)f2bf(a[1]) << 16);
      pk.y = (u32)f2bf(a[2]) | ((u32)f2bf(a[3]) << 16);
      pk.z = (u32)f2bf(a[4]) | ((u32)f2bf(a[5]) << 16);
      pk.w = (u32)f2bf(a[6]) | ((u32)f2bf(a[7]) << 16);
      *(uint4*)&outb[s][co] = pk;
    }
  }
  __syncthreads();
  int ch = t >> 1, s0 = (t & 1) * 4;
  u16 e0 = outb[s0 + 0][ch], e1 = outb[s0 + 1][ch];
  u16 e2 = outb[s0 + 2][ch], e3 = outb[s0 + 3][ch];
  uint2 pk;
  pk.x = (u32)e0 | ((u32)e1 << 16);
  pk.y = (u32)e2 | ((u32)e3 << 16);
  *(uint2*)&feat[(size_t)l * 1024 + ch * 8 + s0] = pk;
}

// ---------------- f32 -> bf16 weight convert ----------------
__global__ __launch_bounds__(256) void k_cvt(const float* __restrict__ src,
                                             u16* __restrict__ dst, int n) {
  int i = (blockIdx.x * 256 + threadIdx.x) * 4;
  if (i >= n) return;
  float4 v = *(const float4*)&src[i];
  uint2 pk;
  pk.x = (u32)f2bf(v.x) | ((u32)f2bf(v.y) << 16);
  pk.y = (u32)f2bf(v.z) | ((u32)f2bf(v.w) << 16);
  *(uint2*)&dst[i] = pk;
}

// ---------------- bf16 GEMM, double-buffered (T3-minimum 2-phase) ----------------
// C = act(A @ B^T + bias). A: MxK bf16, B: NxK bf16. M%128==0, N%128==0, K%32==0.
// One __syncthreads per K-step: STAGE(next buf) issued BEFORE ds_read+MFMA(cur),
// loads drain in the barrier's vmcnt(0). XCD-bijective swizzle (nwg%8==0).
// HEAD==0: coalesced bf16 C store via LDS transpose.
// HEAD==1: no C store; epilogue computes relu(acc+bias)*w3[col], shfl-reduces
//          over col lanes, writes partial[by*2+wc][row] (deterministic, no atomics).
template <int RELU, int HEAD>
__global__ __launch_bounds__(256) void k_gemm(const u16* __restrict__ A,
                                              const u16* __restrict__ B,
                                              const float* __restrict__ bias,
                                              u16* __restrict__ C,
                                              const float* __restrict__ w3,
                                              float* __restrict__ partial,
                                              int M, int N, int K) {
  __shared__ u16 Al[2][4096];
  __shared__ u16 Bl[2][4096];
  int nwg = gridDim.x * gridDim.y;
  int bid = blockIdx.y * gridDim.x + blockIdx.x;
  int cpx = nwg >> 3;
  int key = (bid & 7) * cpx + (bid >> 3);
  int bx = key / gridDim.y;
  int by = key % gridDim.y;
  int t = threadIdx.x, lane = t & 63, wid = t >> 6;
  int wr = wid >> 1, wc = wid & 1;
  f32x4 acc[4][4] = {};
  int arow = t >> 2, apos = (t & 3) * 8;
  const u16* Abase = A + (size_t)(bx * 128) * K;
  const u16* Bbase = B + (size_t)(by * 128) * K;
  int r = lane & 15, ks = (lane >> 4) * 8;
  int nt = K >> 5;
  // prologue: stage tile 0 into buffer 0
  gload_lds16(&Al[0][t * 8],         Abase + (size_t)arow * K + apos);
  gload_lds16(&Al[0][(t + 256) * 8], Abase + (size_t)(arow + 64) * K + apos);
  gload_lds16(&Bl[0][t * 8],         Bbase + (size_t)arow * K + apos);
  gload_lds16(&Bl[0][(t + 256) * 8], Bbase + (size_t)(arow + 64) * K + apos);
  __syncthreads();
  for (int it = 0; it < nt; ++it) {
    int cur = it & 1, nxt = cur ^ 1;
    if (it + 1 < nt) {                 // issue next-tile loads first (overlap MFMA)
      int k0 = (it + 1) << 5;
      gload_lds16(&Al[nxt][t * 8],         Abase + (size_t)arow * K + k0 + apos);
      gload_lds16(&Al[nxt][(t + 256) * 8], Abase + (size_t)(arow + 64) * K + k0 + apos);
      gload_lds16(&Bl[nxt][t * 8],         Bbase + (size_t)arow * K + k0 + apos);
      gload_lds16(&Bl[nxt][(t + 256) * 8], Bbase + (size_t)(arow + 64) * K + k0 + apos);
    }
    bf16x8 af[4], bfr[4];
#pragma unroll
    for (int i = 0; i < 4; ++i) {
      af[i]  = *(const bf16x8*)&Al[cur][(wr * 64 + i * 16 + r) * 32 + ks];
      bfr[i] = *(const bf16x8*)&Bl[cur][(wc * 64 + i * 16 + r) * 32 + ks];
    }
#pragma unroll
    for (int mi = 0; mi < 4; ++mi)
#pragma unroll
      for (int ni = 0; ni < 4; ++ni)
        acc[mi][ni] = __builtin_amdgcn_mfma_f32_16x16x32_bf16(af[mi], bfr[ni], acc[mi][ni], 0, 0, 0);
    __syncthreads();                   // drains this iter's staging loads too
  }
  int rsub = (lane >> 4) * 4, csub = lane & 15;
  if (HEAD == 0) {
    // coalesced epilogue: stage 64-row chunks in LDS (reuse Al = 16KB), uint4 stores
    u16* Ct = &Al[0][0];               // [64][128]
#pragma unroll
    for (int c = 0; c < 2; ++c) {
      if (wr == c) {
#pragma unroll
        for (int mi = 0; mi < 4; ++mi)
#pragma unroll
          for (int ni = 0; ni < 4; ++ni) {
            int col = wc * 64 + ni * 16 + csub;
            float bv = bias[by * 128 + col];
#pragma unroll
            for (int j = 0; j < 4; ++j) {
              float v = acc[mi][ni][j] + bv;
              if (RELU) v = fmaxf(v, 0.f);
              Ct[(mi * 16 + rsub + j) * 128 + col] = f2bf(v);
            }
          }
      }
      __syncthreads();
#pragma unroll
      for (int i = 0; i < 4; ++i) {
        int lin = i * 256 + t;
        int rl = lin >> 4, pc = lin & 15;
        uint4 v = *(const uint4*)&Ct[rl * 128 + pc * 8];
        *(uint4*)&C[(size_t)(bx * 128 + c * 64 + rl) * N + by * 128 + pc * 8] = v;
      }
      __syncthreads();
    }
  } else {
    // head-fused epilogue: per-row partial dot with w3
    float bv[4], wv[4];
#pragma unroll
    for (int ni = 0; ni < 4; ++ni) {
      int col = by * 128 + wc * 64 + ni * 16 + csub;
      bv[ni] = bias[col];
      wv[ni] = w3[col];
    }
#pragma unroll
    for (int mi = 0; mi < 4; ++mi) {
#pragma unroll
      for (int j = 0; j < 4; ++j) {
        float p = 0.f;
#pragma unroll
        for (int ni = 0; ni < 4; ++ni) {
          float v = acc[mi][ni][j] + bv[ni];
          v = fmaxf(v, 0.f);
          p += v * wv[ni];
        }
        p += __shfl_xor(p, 1, 64);
        p += __shfl_xor(p, 2, 64);
        p += __shfl_xor(p, 4, 64);
        p += __shfl_xor(p, 8, 64);
        if (csub == 0) {
          int row = bx * 128 + wr * 64 + mi * 16 + rsub + j;
          partial[(size_t)(by * 2 + wc) * M + row] = p;
        }
      }
    }
  }
}

// ---------------- stage 9: reduce 16 partials -> sigmoid * keep ----------------
__global__ __launch_bounds__(256) void k_head2(const float* __restrict__ partial,
                                               const float* __restrict__ b3,
                                               const float* __restrict__ keepf,
                                               float* __restrict__ scores, int M) {
  int l = blockIdx.x * 256 + threadIdx.x;
  if (l >= NLINES) return;
  float s = 0.f;
#pragma unroll
  for (int i = 0; i < 16; ++i) s += partial[(size_t)i * M + l];
  float logit = s + b3[0];
  scores[l] = keepf[l] / (1.f + expf(-logit));
}

extern "C" void kernel_launch(void* const* d_in, const int* in_sizes, int n_in,
                              void* d_out, int out_size, void* d_ws, size_t ws_size,
                              hipStream_t stream) {
  const float* t_output   = (const float*)d_in[0];
  const float* t_features = (const float*)d_in[1];
  const float* t_lines    = (const float*)d_in[2];
  const float* t_fc1w     = (const float*)d_in[3];
  const float* t_fc1b     = (const float*)d_in[4];
  const float* t_w1       = (const float*)d_in[5];
  const float* t_b1       = (const float*)d_in[6];
  const float* t_w2       = (const float*)d_in[7];
  const float* t_b2       = (const float*)d_in[8];
  const float* t_w3       = (const float*)d_in[9];
  const float* t_b3       = (const float*)d_in[10];

  // workspace layout (~50.6 MB)
  char* w = (char*)d_ws;
  u16*   loib  = (u16*)w;                         // 16384*128 bf16 = 4 MB
  float* jnms  = (float*)(w + 4194304);           // 64 KB
  float* juncs = jnms + HW;                       // 600 f32 (pad 1024)
  float* keepf = juncs + 1024;                    // 10000 f32 (pad 10240)
  u16* fc1wb = (u16*)(keepf + 10240);             // 32768 bf16
  u16* w1b  = fc1wb + 32768;                      // 1M bf16
  u16* w2b  = w1b + 1048576;
  u16* feat = w2b + 1048576;                      // MPAD*1024 bf16
  u16* hid1 = feat + (size_t)MPAD * 1024;
  float* partial = (float*)(hid1 + (size_t)MPAD * 1024);  // 16*MPAD f32
  u16* featT = hid1;                              // alias: consumed before gemm1 writes hid1

  float* out_scores = (float*)d_out;              // 10000
  float* out_ladj   = out_scores + NLINES;        // 40000
  float* out_juncs  = out_scores + 50000;         // 600
  float* out_jsc    = out_scores + 50600;         // 300

  k_nms<<<dim3(8, 8), 256, 0, stream>>>(t_output, jnms);
  k_topk<<<1, 1024, 0, stream>>>(jnms, t_output, juncs, out_juncs, out_jsc);
  k_match<<<2500, 256, 0, stream>>>(juncs, t_lines, out_ladj, keepf);
  k_cvt<<<32, 256, 0, stream>>>(t_fc1w, fc1wb, 32768);
  k_transp<<<dim3(256, 4), 256, 0, stream>>>(t_features, featT);
  k_gemm<0, 0><<<dim3(128, 1), 256, 0, stream>>>(featT, fc1wb, t_fc1b, loib,
                                                 nullptr, nullptr, HW, 128, 256);
  k_interp<<<NLINES, 256, 0, stream>>>(loib, out_ladj, feat);
  k_cvt<<<1024, 256, 0, stream>>>(t_w1, w1b, 1048576);
  k_cvt<<<1024, 256, 0, stream>>>(t_w2, w2b, 1048576);
  k_gemm<1, 0><<<dim3(MPAD / 128, 8), 256, 0, stream>>>(feat, w1b, t_b1, hid1,
                                                        nullptr, nullptr, MPAD, 1024, 1024);
  k_gemm<1, 1><<<dim3(MPAD / 128, 8), 256, 0, stream>>>(hid1, w2b, t_b2, nullptr,
                                                        t_w3, partial, MPAD, 1024, 1024);
  k_head2<<<40, 256, 0, stream>>>(partial, t_b3, keepf, out_scores, MPAD);
}